// Round 1
// baseline (567.121 us; speedup 1.0000x reference)
//
#include <hip/hip_runtime.h>
#include <hip/hip_bf16.h>
#include <cstdint>

typedef unsigned short u16;
typedef __attribute__((ext_vector_type(8))) short short8;
typedef __attribute__((ext_vector_type(4))) float f32x4;

#define HW_N 16384   // H*W
#define CCH  256     // C
#define BATCH 8
#define NHEAD 8
#define HEADC 32

static __device__ __forceinline__ float bf2f(u16 u){
    union { float f; uint32_t i; } x; x.i = ((uint32_t)u) << 16; return x.f;
}
static __device__ __forceinline__ u16 f2bf(float f){
    union { float f; uint32_t i; } x; x.f = f;
    uint32_t r = x.i + 0x7fffu + ((x.i >> 16) & 1u);   // round-to-nearest-even
    return (u16)(r >> 16);
}

// ---------------------------------------------------------------------------
// K0a: x [B,C,N] fp32 -> xb [B*N, C] bf16  (transpose + cast, LDS-tiled)
// ---------------------------------------------------------------------------
__global__ __launch_bounds__(256) void k_transpose_cast(const float* __restrict__ x,
                                                        u16* __restrict__ xb){
    __shared__ float tile[64][65];
    int b = blockIdx.z, ct = blockIdx.y, nt = blockIdx.x;
    int t = threadIdx.x;
    const float* src = x + ((size_t)b * CCH + ct * 64) * HW_N + nt * 64;
    #pragma unroll
    for (int it = 0; it < 16; ++it){
        int f = it * 256 + t;
        int i = f >> 6, j = f & 63;              // i = c-local, j = n-local
        tile[i][j] = src[(size_t)i * HW_N + j];  // coalesced (j fastest)
    }
    __syncthreads();
    u16* dst = xb + ((size_t)b * HW_N + nt * 64) * CCH + ct * 64;
    #pragma unroll
    for (int it = 0; it < 16; ++it){
        int f = it * 256 + t;
        int jj = f >> 6, ii = f & 63;            // jj = n-local, ii = c-local
        dst[(size_t)jj * CCH + ii] = f2bf(tile[ii][jj]);  // coalesced writes
    }
}

// ---------------------------------------------------------------------------
// K0b: weight prep. wkv_b[h*64 + s*32 + d] <- w_qkv row (h*96 + 32 + s*32 + d)
//      (s=0 -> k, s=1 -> v); casts w_o1/w_o2; rearranged k/v bias.
// ---------------------------------------------------------------------------
__global__ __launch_bounds__(256) void k_weight_prep(const float* __restrict__ w_qkv,
                                                     const float* __restrict__ b_qkv,
                                                     const float* __restrict__ w_o1,
                                                     const float* __restrict__ w_o2,
                                                     u16* __restrict__ wkv_b,
                                                     float* __restrict__ bkv_re,
                                                     u16* __restrict__ w_o1_b,
                                                     u16* __restrict__ w_o2_b){
    int id = blockIdx.x * 256 + threadIdx.x;
    if (id < 512 * 256){
        int r = id >> 8, c = id & 255;
        int h = r >> 6, s = (r >> 5) & 1, d = r & 31;
        int srow = h * 96 + 32 + s * 32 + d;
        wkv_b[id] = f2bf(w_qkv[(size_t)srow * 256 + c]);
        if (c == 0) bkv_re[r] = b_qkv[srow];
    } else {
        int id2 = id - 512 * 256;
        if (id2 < 65536)       w_o1_b[id2]         = f2bf(w_o1[id2]);
        else if (id2 < 131072) w_o2_b[id2 - 65536] = f2bf(w_o2[id2 - 65536]);
    }
}

// ---------------------------------------------------------------------------
// Shared MFMA GEMM:  out[n, o] = bf16( act( sum_c A[n,c]*Bt[o,c] + bias[o]
//                                           (+ resid[n,o]) ) )
// A: [B*Mb, 256] bf16, k-contiguous rows.  Bt: [NC, 256] bf16 (+ z*bt_stride).
// 128x128 tile, BK=64, 4 waves (2x2), 16x16x32 bf16 MFMA, single-buffer LDS.
// Fragment layout per guide §3 (m89/m97-verified):
//   A/B frag: lane holds 8 contiguous k at row = lane&15, k0 = (lane>>4)*8
//   C/D:      col = lane&15, row = (lane>>4)*4 + reg
// ---------------------------------------------------------------------------
template<bool GELU, bool RESID>
__global__ __launch_bounds__(256) void k_gemm(const u16* __restrict__ A,
                                              const u16* __restrict__ Bt0,
                                              const float* __restrict__ bias0,
                                              const u16* __restrict__ resid,
                                              u16* __restrict__ out,
                                              int NC, int Mb,
                                              long bt_stride, int bias_stride){
    __shared__ u16 lsA[128 * 64];
    __shared__ u16 lsB[128 * 64];
    int z = blockIdx.z;
    int row0 = z * Mb + blockIdx.y * 128;
    int col0 = blockIdx.x * 128;
    const u16* Bt = Bt0 + (size_t)z * bt_stride;
    const float* bias = bias0 ? (bias0 + (size_t)z * bias_stride) : nullptr;

    int t = threadIdx.x;
    int wid = t >> 6, lane = t & 63;
    int wr = wid >> 1, wc = wid & 1;     // 2x2 wave grid over 128x128 tile

    f32x4 acc[4][4];
    #pragma unroll
    for (int i = 0; i < 4; ++i)
        #pragma unroll
        for (int j = 0; j < 4; ++j) acc[i][j] = (f32x4)0.0f;

    for (int kt = 0; kt < 4; ++kt){
        int c0 = kt * 64;
        // ---- stage A/B tiles: 16KB each, 4 x 16B per thread ----
        #pragma unroll
        for (int it = 0; it < 4; ++it){
            int f = it * 256 + t;
            int r = f >> 3, c8 = (f & 7) * 8;
            *(uint4*)&lsA[f * 8] = *(const uint4*)&A [((size_t)(row0 + r)) * 256 + c0 + c8];
            *(uint4*)&lsB[f * 8] = *(const uint4*)&Bt[((size_t)(col0 + r)) * 256 + c0 + c8];
        }
        __syncthreads();
        int lrow = lane & 15;
        #pragma unroll
        for (int ks = 0; ks < 2; ++ks){
            int lk = (lane >> 4) * 8 + ks * 32;
            short8 af[4], bfr[4];
            #pragma unroll
            for (int mi = 0; mi < 4; ++mi)
                af[mi] = *(const short8*)&lsA[(wr * 64 + mi * 16 + lrow) * 64 + lk];
            #pragma unroll
            for (int ni = 0; ni < 4; ++ni)
                bfr[ni] = *(const short8*)&lsB[(wc * 64 + ni * 16 + lrow) * 64 + lk];
            #pragma unroll
            for (int mi = 0; mi < 4; ++mi)
                #pragma unroll
                for (int ni = 0; ni < 4; ++ni)
                    acc[mi][ni] = __builtin_amdgcn_mfma_f32_16x16x32_bf16(
                        af[mi], bfr[ni], acc[mi][ni], 0, 0, 0);
        }
        __syncthreads();
    }

    // ---- epilogue ----
    int lrow = lane & 15;
    int rowq = (lane >> 4) * 4;
    #pragma unroll
    for (int ni = 0; ni < 4; ++ni){
        int gcol = col0 + wc * 64 + ni * 16 + lrow;
        float bv = bias ? bias[gcol] : 0.0f;
        #pragma unroll
        for (int mi = 0; mi < 4; ++mi){
            #pragma unroll
            for (int r = 0; r < 4; ++r){
                int grow = row0 + wr * 64 + mi * 16 + rowq + r;
                float v = acc[mi][ni][r] + bv;
                if (RESID) v += bf2f(resid[(size_t)grow * NC + gcol]);
                if (GELU)  v = 0.5f * v * (1.0f + erff(v * 0.70710678118654752f));
                out[(size_t)grow * NC + gcol] = f2bf(v);
            }
        }
    }
}

// ---------------------------------------------------------------------------
// K1b: per-head LayerNorm of k,v + kv = sum_n k_ln^T v_ln  (block partials)
// Block = (b, 512-n range as 2 chunks of 256), thread = one n.
// kvpart layout: [b][g=32][h=8][1024], element (d*32+e) at t*4+i (t=d*8+e/4)
// ---------------------------------------------------------------------------
__global__ __launch_bounds__(256) void k_ln_kv(const u16* __restrict__ kvraw,
                                               const float* __restrict__ kln_w,
                                               const float* __restrict__ kln_b,
                                               const float* __restrict__ vln_w,
                                               const float* __restrict__ vln_b,
                                               float* __restrict__ kvpart){
    __shared__ float lk[32][260];   // [d][n], padded: d-row stride 260 words
    __shared__ float lv[32][260];
    int g = blockIdx.x;   // 0..31
    int b = blockIdx.y;
    int t = threadIdx.x;
    int dmy = t >> 3, e0 = (t & 7) * 4;

    float accp[8][4];
    #pragma unroll
    for (int h = 0; h < 8; ++h)
        #pragma unroll
        for (int i = 0; i < 4; ++i) accp[h][i] = 0.0f;

    for (int ch = 0; ch < 2; ++ch){
        int n = g * 512 + ch * 256 + t;
        const u16* rowp = kvraw + ((size_t)b * HW_N + n) * 512;
        #pragma unroll
        for (int h = 0; h < 8; ++h){
            float kx[32], vx[32];
            #pragma unroll
            for (int q = 0; q < 4; ++q){
                short8 sk = *(const short8*)&rowp[h * 64 + q * 8];
                short8 sv = *(const short8*)&rowp[h * 64 + 32 + q * 8];
                #pragma unroll
                for (int j = 0; j < 8; ++j){
                    kx[q * 8 + j] = bf2f((u16)sk[j]);
                    vx[q * 8 + j] = bf2f((u16)sv[j]);
                }
            }
            // LayerNorm over 32 channels (fp32, in-register)
            float muk = 0.f, muv = 0.f;
            #pragma unroll
            for (int d = 0; d < 32; ++d){ muk += kx[d]; muv += vx[d]; }
            muk *= (1.0f / 32.0f); muv *= (1.0f / 32.0f);
            float vark = 0.f, varv = 0.f;
            #pragma unroll
            for (int d = 0; d < 32; ++d){
                float dk = kx[d] - muk, dv = vx[d] - muv;
                vark += dk * dk; varv += dv * dv;
            }
            float rsk = rsqrtf(vark * (1.0f / 32.0f) + 1e-5f);
            float rsv = rsqrtf(varv * (1.0f / 32.0f) + 1e-5f);
            #pragma unroll
            for (int d = 0; d < 32; ++d){
                kx[d] = (kx[d] - muk) * rsk * kln_w[h * 32 + d] + kln_b[h * 32 + d];
                vx[d] = (vx[d] - muv) * rsv * vln_w[h * 32 + d] + vln_b[h * 32 + d];
            }
            __syncthreads();   // protect previous iteration's readers
            #pragma unroll
            for (int d = 0; d < 32; ++d){ lk[d][t] = kx[d]; lv[d][t] = vx[d]; }
            __syncthreads();
            // pair reduce: this thread owns (d = t>>3, e = e0..e0+3)
            float a0 = 0.f, a1 = 0.f, a2 = 0.f, a3 = 0.f;
            for (int n4 = 0; n4 < 64; ++n4){
                f32x4 kk = *(const f32x4*)&lk[dmy][n4 * 4];
                f32x4 v0 = *(const f32x4*)&lv[e0 + 0][n4 * 4];
                f32x4 v1 = *(const f32x4*)&lv[e0 + 1][n4 * 4];
                f32x4 v2 = *(const f32x4*)&lv[e0 + 2][n4 * 4];
                f32x4 v3 = *(const f32x4*)&lv[e0 + 3][n4 * 4];
                a0 += kk.x * v0.x + kk.y * v0.y + kk.z * v0.z + kk.w * v0.w;
                a1 += kk.x * v1.x + kk.y * v1.y + kk.z * v1.z + kk.w * v1.w;
                a2 += kk.x * v2.x + kk.y * v2.y + kk.z * v2.z + kk.w * v2.w;
                a3 += kk.x * v3.x + kk.y * v3.y + kk.z * v3.z + kk.w * v3.w;
            }
            accp[h][0] += a0; accp[h][1] += a1; accp[h][2] += a2; accp[h][3] += a3;
        }
    }
    float* dst = kvpart + (((size_t)b * 32 + g) * 8) * 1024;
    #pragma unroll
    for (int h = 0; h < 8; ++h)
        #pragma unroll
        for (int i = 0; i < 4; ++i)
            dst[h * 1024 + t * 4 + i] = accp[h][i];
}

// ---------------------------------------------------------------------------
// K2: reduce kv partials, form wq_eff[b,h,e,c] = sum_d wq[d,c]*kv_n[d,e]
//     and beff[b,h,e] = sum_d bq[d]*kv_n[d,e]
// ---------------------------------------------------------------------------
__global__ __launch_bounds__(256) void k_wqeff(const float* __restrict__ kvpart,
                                               const float* __restrict__ w_qkv,
                                               const float* __restrict__ b_qkv,
                                               u16* __restrict__ wq_eff_b,
                                               float* __restrict__ beff){
    __shared__ float kv[1024];   // [d*32 + e]
    int h = blockIdx.x, b = blockIdx.y;
    int t = threadIdx.x;
    float s[4] = {0.f, 0.f, 0.f, 0.f};
    for (int p = 0; p < 32; ++p){
        const float* src = kvpart + (((size_t)b * 32 + p) * 8 + h) * 1024 + t * 4;
        #pragma unroll
        for (int i = 0; i < 4; ++i) s[i] += src[i];
    }
    const float invN = 1.0f / (float)HW_N;
    #pragma unroll
    for (int i = 0; i < 4; ++i) kv[t * 4 + i] = s[i] * invN;
    __syncthreads();

    float wcol[32];
    #pragma unroll
    for (int d = 0; d < 32; ++d)
        wcol[d] = w_qkv[((size_t)(h * 96 + d)) * 256 + t];   // q rows, coalesced
    for (int e = 0; e < 32; ++e){
        float s2 = 0.f;
        #pragma unroll
        for (int d = 0; d < 32; ++d) s2 += wcol[d] * kv[d * 32 + e];
        wq_eff_b[(((size_t)b * 256) + h * 32 + e) * 256 + t] = f2bf(s2);
    }
    if (t < 32){
        float s3 = 0.f;
        #pragma unroll
        for (int d = 0; d < 32; ++d) s3 += b_qkv[h * 96 + d] * kv[d * 32 + t];
        beff[b * 256 + h * 32 + t] = s3;
    }
}

// ---------------------------------------------------------------------------
// K6: out[b,o,n] = y2b[n,o] + x[b,o,n]   (transpose back + final residual)
// ---------------------------------------------------------------------------
__global__ __launch_bounds__(256) void k_out_trans(const u16* __restrict__ y2b,
                                                   const float* __restrict__ x,
                                                   float* __restrict__ out){
    __shared__ float tile[64][65];
    int b = blockIdx.z, ot = blockIdx.y, nt = blockIdx.x;
    int t = threadIdx.x;
    const u16* src = y2b + ((size_t)b * HW_N + nt * 64) * 256 + ot * 64;
    #pragma unroll
    for (int it = 0; it < 16; ++it){
        int f = it * 256 + t;
        int i = f >> 6, j = f & 63;   // i = n-local, j = o-local
        tile[i][j] = bf2f(src[(size_t)i * 256 + j]);
    }
    __syncthreads();
    size_t obase = ((size_t)b * 256 + ot * 64) * HW_N + (size_t)nt * 64;
    #pragma unroll
    for (int it = 0; it < 16; ++it){
        int f = it * 256 + t;
        int jj = f >> 6, ii = f & 63; // jj = o-local, ii = n-local
        size_t idx = obase + (size_t)jj * HW_N + ii;
        out[idx] = tile[ii][jj] + x[idx];
    }
}

// ---------------------------------------------------------------------------
extern "C" void kernel_launch(void* const* d_in, const int* in_sizes, int n_in,
                              void* d_out, int out_size, void* d_ws, size_t ws_size,
                              hipStream_t stream){
    const float* x     = (const float*)d_in[0];
    const float* w_qkv = (const float*)d_in[1];
    const float* b_qkv = (const float*)d_in[2];
    const float* kln_w = (const float*)d_in[3];
    const float* kln_b = (const float*)d_in[4];
    const float* vln_w = (const float*)d_in[5];
    const float* vln_b = (const float*)d_in[6];
    const float* w_o1  = (const float*)d_in[7];
    const float* b_o1  = (const float*)d_in[8];
    const float* w_o2  = (const float*)d_in[9];
    const float* b_o2  = (const float*)d_in[10];
    float* out = (float*)d_out;

    const size_t MB = 1u << 20;
    // workspace map (~266 MB):
    //   [0,64M)    xb        bf16 [B*N,256]
    //   [64M,192M) kvraw     bf16 [B*N,512]; later y1b@64M (64MB), y2b@128M (64MB)
    //   [192M,256M) ret_b    bf16 [B*N,256]
    //   [256M,264M) kvpart   fp32 [B][32][8][1024]
    //   [264M,..)  small: wkv_b, bkv_re, w_o1_b, w_o2_b, wq_eff_b, beff
    if (ws_size < 266 * MB) return;   // loud failure if workspace too small

    char* ws = (char*)d_ws;
    u16*   xb      = (u16*)(ws);
    u16*   kvraw   = (u16*)(ws + 64 * MB);
    u16*   y1b     = (u16*)(ws + 64 * MB);
    u16*   y2b     = (u16*)(ws + 128 * MB);
    u16*   ret_b   = (u16*)(ws + 192 * MB);
    float* kvpart  = (float*)(ws + 256 * MB);
    char*  sm      = ws + 264 * MB;
    u16*   wkv_b   = (u16*)sm;                       // 512*256*2 = 256KB
    float* bkv_re  = (float*)(sm + 256 * 1024);      // 2KB
    u16*   w_o1_b  = (u16*)(sm + 260 * 1024);        // 128KB
    u16*   w_o2_b  = (u16*)(sm + 392 * 1024);        // 128KB
    u16*   wq_effb = (u16*)(sm + 524 * 1024);        // 8*256*256*2 = 1MB
    float* beff    = (float*)(sm + 1572 * 1024);     // 8KB

    // K0a: transpose+cast x -> xb
    k_transpose_cast<<<dim3(HW_N / 64, CCH / 64, BATCH), 256, 0, stream>>>(x, xb);
    // K0b: weight prep
    k_weight_prep<<<dim3(1024), 256, 0, stream>>>(w_qkv, b_qkv, w_o1, w_o2,
                                                  wkv_b, bkv_re, w_o1_b, w_o2_b);
    // K1a: k/v projection GEMM -> kvraw [B*N, 512] (bias added pre-LN)
    k_gemm<false, false><<<dim3(4, 128, BATCH), 256, 0, stream>>>(
        xb, wkv_b, bkv_re, nullptr, kvraw, 512, HW_N, 0, 0);
    // K1b: LN + kv partial sums
    k_ln_kv<<<dim3(32, BATCH), 256, 0, stream>>>(kvraw, kln_w, kln_b, vln_w, vln_b, kvpart);
    // K2: reduce partials, build per-batch effective q-weights
    k_wqeff<<<dim3(NHEAD, BATCH), 256, 0, stream>>>(kvpart, w_qkv, b_qkv, wq_effb, beff);
    // K3: att = x @ wq_eff^T + beff ; ret = att + x   (per-batch Bt)
    k_gemm<false, true><<<dim3(2, 128, BATCH), 256, 0, stream>>>(
        xb, wq_effb, beff, xb, ret_b, 256, HW_N, 65536, 256);
    // K4: y1 = gelu(ret @ w_o1^T + b_o1)
    k_gemm<true, false><<<dim3(2, 128, BATCH), 256, 0, stream>>>(
        ret_b, w_o1_b, b_o1, nullptr, y1b, 256, HW_N, 0, 0);
    // K5: y2 = y1 @ w_o2^T + b_o2
    k_gemm<false, false><<<dim3(2, 128, BATCH), 256, 0, stream>>>(
        y1b, w_o2_b, b_o2, nullptr, y2b, 256, HW_N, 0, 0);
    // K6: out = y2^T + x
    k_out_trans<<<dim3(HW_N / 64, CCH / 64, BATCH), 256, 0, stream>>>(y2b, x, out);
}

// Round 2
// 369.864 us; speedup vs baseline: 1.5333x; 1.5333x over previous
//
#include <hip/hip_runtime.h>
#include <hip/hip_bf16.h>
#include <cstdint>

typedef unsigned short u16;
typedef __attribute__((ext_vector_type(8))) short short8;
typedef __attribute__((ext_vector_type(4))) float f32x4;

#define HW_N 16384   // H*W
#define CCH  256     // C
#define BATCH 8
#define NHEAD 8
#define HEADC 32

static __device__ __forceinline__ float bf2f(u16 u){
    union { float f; uint32_t i; } x; x.i = ((uint32_t)u) << 16; return x.f;
}
static __device__ __forceinline__ u16 f2bf(float f){
    union { float f; uint32_t i; } x; x.f = f;
    uint32_t r = x.i + 0x7fffu + ((x.i >> 16) & 1u);   // round-to-nearest-even
    return (u16)(r >> 16);
}

#define GLD16(gp, lp) __builtin_amdgcn_global_load_lds( \
    (const __attribute__((address_space(1))) uint32_t*)(gp), \
    (__attribute__((address_space(3))) uint32_t*)(lp), 16, 0, 0)

// ---------------------------------------------------------------------------
// K0a: x [B,C,N] fp32 -> xb [B*N, C] bf16  (transpose + cast, LDS-tiled)
// ---------------------------------------------------------------------------
__global__ __launch_bounds__(256) void k_transpose_cast(const float* __restrict__ x,
                                                        u16* __restrict__ xb){
    __shared__ float tile[64][65];
    int b = blockIdx.z, ct = blockIdx.y, nt = blockIdx.x;
    int t = threadIdx.x;
    const float* src = x + ((size_t)b * CCH + ct * 64) * HW_N + nt * 64;
    #pragma unroll
    for (int it = 0; it < 16; ++it){
        int f = it * 256 + t;
        int i = f >> 6, j = f & 63;              // i = c-local, j = n-local
        tile[i][j] = src[(size_t)i * HW_N + j];  // coalesced (j fastest)
    }
    __syncthreads();
    u16* dst = xb + ((size_t)b * HW_N + nt * 64) * CCH + ct * 64;
    #pragma unroll
    for (int it = 0; it < 16; ++it){
        int f = it * 256 + t;
        int jj = f >> 6, ii = f & 63;            // jj = n-local, ii = c-local
        dst[(size_t)jj * CCH + ii] = f2bf(tile[ii][jj]);  // coalesced writes
    }
}

// ---------------------------------------------------------------------------
// K0b: weight prep. wkv_b[h*64 + s*32 + d] <- w_qkv row (h*96 + 32 + s*32 + d)
// ---------------------------------------------------------------------------
__global__ __launch_bounds__(256) void k_weight_prep(const float* __restrict__ w_qkv,
                                                     const float* __restrict__ b_qkv,
                                                     const float* __restrict__ w_o1,
                                                     const float* __restrict__ w_o2,
                                                     u16* __restrict__ wkv_b,
                                                     float* __restrict__ bkv_re,
                                                     u16* __restrict__ w_o1_b,
                                                     u16* __restrict__ w_o2_b){
    int id = blockIdx.x * 256 + threadIdx.x;
    if (id < 512 * 256){
        int r = id >> 8, c = id & 255;
        int h = r >> 6, s = (r >> 5) & 1, d = r & 31;
        int srow = h * 96 + 32 + s * 32 + d;
        wkv_b[id] = f2bf(w_qkv[(size_t)srow * 256 + c]);
        if (c == 0) bkv_re[r] = b_qkv[srow];
    } else {
        int id2 = id - 512 * 256;
        if (id2 < 65536)       w_o1_b[id2]         = f2bf(w_o1[id2]);
        else if (id2 < 131072) w_o2_b[id2 - 65536] = f2bf(w_o2[id2 - 65536]);
    }
}

// ---------------------------------------------------------------------------
// Shared MFMA GEMM:  out[n, o] = bf16( act( sum_c A[n,c]*Bt[o,c] + bias[o]
//                                           (+ resid[n,o]) ) )
// 128x128 tile, BK=64, 4 waves (2x2), 16x16x32 bf16 MFMA.
// Staging via global_load_lds width=16 (linear LDS dest) with XOR-swizzled
// global source; ds_read_b128 applies the same involution:
//   elem ^= (row&7)<<3  <=>  byte ^= (row&7)<<4   (rows are 128 B)
// ---------------------------------------------------------------------------
template<bool GELU, bool RESID>
__global__ __launch_bounds__(256) void k_gemm(const u16* __restrict__ A,
                                              const u16* __restrict__ Bt0,
                                              const float* __restrict__ bias0,
                                              const u16* __restrict__ resid,
                                              u16* __restrict__ out,
                                              int NC, int Mb,
                                              long bt_stride, int bias_stride){
    __shared__ __align__(16) u16 lsA[128 * 64];
    __shared__ __align__(16) u16 lsB[128 * 64];
    int z = blockIdx.z;
    int row0 = z * Mb + blockIdx.y * 128;
    int col0 = blockIdx.x * 128;
    const u16* Bt = Bt0 + (size_t)z * bt_stride;
    const float* bias = bias0 ? (bias0 + (size_t)z * bias_stride) : nullptr;

    int t = threadIdx.x;
    int wid = t >> 6, lane = t & 63;
    int wr = wid >> 1, wc = wid & 1;     // 2x2 wave grid over 128x128 tile

    f32x4 acc[4][4];
    #pragma unroll
    for (int i = 0; i < 4; ++i)
        #pragma unroll
        for (int j = 0; j < 4; ++j) acc[i][j] = (f32x4)0.0f;

    for (int kt = 0; kt < 4; ++kt){
        int c0 = kt * 64;
        // ---- stage A/B tiles via async global->LDS, 16B/lane, swizzled src ----
        #pragma unroll
        for (int it = 0; it < 4; ++it){
            int f  = it * 256 + t;
            int fs = f ^ ((f >> 3) & 7);           // inverse-swizzle the source
            int r  = f >> 3, c8 = (fs & 7) * 8;
            GLD16(&A [((size_t)(row0 + r)) * 256 + c0 + c8], &lsA[f * 8]);
            GLD16(&Bt[((size_t)(col0 + r)) * 256 + c0 + c8], &lsB[f * 8]);
        }
        __syncthreads();
        int lrow = lane & 15;
        #pragma unroll
        for (int ks = 0; ks < 2; ++ks){
            int lk = (lane >> 4) * 8 + ks * 32;
            short8 af[4], bfr[4];
            #pragma unroll
            for (int mi = 0; mi < 4; ++mi){
                int row = wr * 64 + mi * 16 + lrow;
                int e = (row * 64 + lk) ^ ((row & 7) << 3);
                af[mi] = *(const short8*)&lsA[e];
            }
            #pragma unroll
            for (int ni = 0; ni < 4; ++ni){
                int row = wc * 64 + ni * 16 + lrow;
                int e = (row * 64 + lk) ^ ((row & 7) << 3);
                bfr[ni] = *(const short8*)&lsB[e];
            }
            #pragma unroll
            for (int mi = 0; mi < 4; ++mi)
                #pragma unroll
                for (int ni = 0; ni < 4; ++ni)
                    acc[mi][ni] = __builtin_amdgcn_mfma_f32_16x16x32_bf16(
                        af[mi], bfr[ni], acc[mi][ni], 0, 0, 0);
        }
        __syncthreads();
    }

    // ---- epilogue ----
    int lrow = lane & 15;
    int rowq = (lane >> 4) * 4;
    #pragma unroll
    for (int ni = 0; ni < 4; ++ni){
        int gcol = col0 + wc * 64 + ni * 16 + lrow;
        float bv = bias ? bias[gcol] : 0.0f;
        #pragma unroll
        for (int mi = 0; mi < 4; ++mi){
            #pragma unroll
            for (int r = 0; r < 4; ++r){
                int grow = row0 + wr * 64 + mi * 16 + rowq + r;
                float v = acc[mi][ni][r] + bv;
                if (RESID) v += bf2f(resid[(size_t)grow * NC + gcol]);
                if (GELU)  v = 0.5f * v * (1.0f + erff(v * 0.70710678118654752f));
                out[(size_t)grow * NC + gcol] = f2bf(v);
            }
        }
    }
}

// ---------------------------------------------------------------------------
// K1b v2: per-head LN of k,v + kv partial via MFMA.
// Grid: (64 chunks, B). Block: 256 thr = 4 waves, 256 n per block.
// Per head-phase:
//   stage 2 x (128 rows x 128 B) coalesced -> LDS raw
//   LN in regs: waves 0-1 handle k (s=0), waves 2-3 handle v (s=1)
//   write LN'd bf16 transposed -> lkt/lvt [32][264] (2-way banks = free)
//   MFMA: wave w reduces n in [w*64, w*64+64): kv_part = ktile @ vtile^T
//   cross-wave sum via pkv (aliases staging) -> kvpart[b][chunk][h][1024]
// ---------------------------------------------------------------------------
__global__ __launch_bounds__(256) void k_ln_kv(const u16* __restrict__ kvraw,
                                               const float* __restrict__ kln_w,
                                               const float* __restrict__ kln_b,
                                               const float* __restrict__ vln_w,
                                               const float* __restrict__ vln_b,
                                               float* __restrict__ kvpart){
    union ShU { u16 raw[128 * 72]; float pkv[4096]; };
    __shared__ __align__(16) ShU sh;
    __shared__ __align__(16) u16 lkt[32 * 264];
    __shared__ __align__(16) u16 lvt[32 * 264];

    int t = threadIdx.x, lane = t & 63, wid = t >> 6;
    int b = blockIdx.y, ch = blockIdx.x;          // ch: 0..63
    size_t nbase = (size_t)b * HW_N + (size_t)ch * 256;
    int s = t >> 7, nl = t & 127;                 // s: 0=k, 1=v
    const float* lnw = s ? vln_w : kln_w;
    const float* lnb = s ? vln_b : kln_b;
    u16* ldst = s ? lvt : lkt;

    for (int h = 0; h < 8; ++h){
        for (int sub = 0; sub < 2; ++sub){
            __syncthreads();   // protects sh.raw reuse (prev LN reads / pkv reads)
            // ---- coalesced stage: 128 rows x 128 B of head h's k|v slice ----
            #pragma unroll
            for (int it = 0; it < 4; ++it){
                int f = it * 256 + t;             // 0..1023
                int r = f >> 3, c = f & 7;
                const u16* g = kvraw + (nbase + sub * 128 + r) * 512 + h * 64 + c * 8;
                *(uint4*)&sh.raw[r * 72 + c * 8] = *(const uint4*)g;
            }
            __syncthreads();
            // ---- LN for (s, n = sub*128 + nl) over 32 channels ----
            float xr[32];
            #pragma unroll
            for (int q = 0; q < 4; ++q){
                short8 v8 = *(const short8*)&sh.raw[nl * 72 + s * 32 + q * 8];
                #pragma unroll
                for (int j = 0; j < 8; ++j) xr[q * 8 + j] = bf2f((u16)v8[j]);
            }
            float mu = 0.f;
            #pragma unroll
            for (int d = 0; d < 32; ++d) mu += xr[d];
            mu *= (1.0f / 32.0f);
            float var = 0.f;
            #pragma unroll
            for (int d = 0; d < 32; ++d){ float dd = xr[d] - mu; var += dd * dd; }
            float rs = rsqrtf(var * (1.0f / 32.0f) + 1e-5f);
            #pragma unroll
            for (int d = 0; d < 32; ++d){
                float o = (xr[d] - mu) * rs * lnw[h * 32 + d] + lnb[h * 32 + d];
                ldst[d * 264 + sub * 128 + nl] = f2bf(o);
            }
        }
        __syncthreads();   // lkt/lvt complete; sh.raw free (-> pkv)
        // ---- MFMA reduce: wave wid owns n in [wid*64, wid*64+64) ----
        int lrow = lane & 15, g = lane >> 4;
        f32x4 acc[2][2];
        #pragma unroll
        for (int i = 0; i < 2; ++i)
            #pragma unroll
            for (int j = 0; j < 2; ++j) acc[i][j] = (f32x4)0.0f;
        #pragma unroll
        for (int ks = 0; ks < 2; ++ks){
            int col = wid * 64 + ks * 32 + g * 8;
            short8 af0 = *(const short8*)&lkt[lrow * 264 + col];
            short8 af1 = *(const short8*)&lkt[(16 + lrow) * 264 + col];
            short8 bf0 = *(const short8*)&lvt[lrow * 264 + col];
            short8 bf1 = *(const short8*)&lvt[(16 + lrow) * 264 + col];
            acc[0][0] = __builtin_amdgcn_mfma_f32_16x16x32_bf16(af0, bf0, acc[0][0], 0, 0, 0);
            acc[0][1] = __builtin_amdgcn_mfma_f32_16x16x32_bf16(af0, bf1, acc[0][1], 0, 0, 0);
            acc[1][0] = __builtin_amdgcn_mfma_f32_16x16x32_bf16(af1, bf0, acc[1][0], 0, 0, 0);
            acc[1][1] = __builtin_amdgcn_mfma_f32_16x16x32_bf16(af1, bf1, acc[1][1], 0, 0, 0);
        }
        #pragma unroll
        for (int mi = 0; mi < 2; ++mi)
            #pragma unroll
            for (int ni = 0; ni < 2; ++ni)
                #pragma unroll
                for (int r = 0; r < 4; ++r){
                    int d = mi * 16 + g * 4 + r, e = ni * 16 + lrow;
                    sh.pkv[wid * 1024 + d * 32 + e] = acc[mi][ni][r];
                }
        __syncthreads();
        // ---- cross-wave sum + store partial for this (b, chunk, head) ----
        f32x4 a0 = *(const f32x4*)&sh.pkv[t * 4];
        f32x4 a1 = *(const f32x4*)&sh.pkv[1024 + t * 4];
        f32x4 a2 = *(const f32x4*)&sh.pkv[2048 + t * 4];
        f32x4 a3 = *(const f32x4*)&sh.pkv[3072 + t * 4];
        f32x4 s4 = a0 + a1 + a2 + a3;
        *(f32x4*)(kvpart + (((size_t)b * 64 + ch) * 8 + h) * 1024 + t * 4) = s4;
    }
}

// ---------------------------------------------------------------------------
// K2: reduce kv partials (64 chunks), form wq_eff[b,h,e,c] and beff[b,h,e]
// ---------------------------------------------------------------------------
__global__ __launch_bounds__(256) void k_wqeff(const float* __restrict__ kvpart,
                                               const float* __restrict__ w_qkv,
                                               const float* __restrict__ b_qkv,
                                               u16* __restrict__ wq_eff_b,
                                               float* __restrict__ beff){
    __shared__ float kv[1024];   // [d*32 + e]
    int h = blockIdx.x, b = blockIdx.y;
    int t = threadIdx.x;
    f32x4 s = (f32x4)0.0f;
    for (int p = 0; p < 64; ++p){
        f32x4 v = *(const f32x4*)(kvpart + (((size_t)b * 64 + p) * 8 + h) * 1024 + t * 4);
        s = s + v;
    }
    const float invN = 1.0f / (float)HW_N;
    #pragma unroll
    for (int i = 0; i < 4; ++i) kv[t * 4 + i] = s[i] * invN;
    __syncthreads();

    float wcol[32];
    #pragma unroll
    for (int d = 0; d < 32; ++d)
        wcol[d] = w_qkv[((size_t)(h * 96 + d)) * 256 + t];   // q rows, coalesced
    for (int e = 0; e < 32; ++e){
        float s2 = 0.f;
        #pragma unroll
        for (int d = 0; d < 32; ++d) s2 += wcol[d] * kv[d * 32 + e];
        wq_eff_b[(((size_t)b * 256) + h * 32 + e) * 256 + t] = f2bf(s2);
    }
    if (t < 32){
        float s3 = 0.f;
        #pragma unroll
        for (int d = 0; d < 32; ++d) s3 += b_qkv[h * 96 + d] * kv[d * 32 + t];
        beff[b * 256 + h * 32 + t] = s3;
    }
}

// ---------------------------------------------------------------------------
// K6: out[b,o,n] = y2b[n,o] + x[b,o,n]   (transpose back + final residual)
// ---------------------------------------------------------------------------
__global__ __launch_bounds__(256) void k_out_trans(const u16* __restrict__ y2b,
                                                   const float* __restrict__ x,
                                                   float* __restrict__ out){
    __shared__ float tile[64][65];
    int b = blockIdx.z, ot = blockIdx.y, nt = blockIdx.x;
    int t = threadIdx.x;
    const u16* src = y2b + ((size_t)b * HW_N + nt * 64) * 256 + ot * 64;
    #pragma unroll
    for (int it = 0; it < 16; ++it){
        int f = it * 256 + t;
        int i = f >> 6, j = f & 63;   // i = n-local, j = o-local
        tile[i][j] = bf2f(src[(size_t)i * 256 + j]);
    }
    __syncthreads();
    size_t obase = ((size_t)b * 256 + ot * 64) * HW_N + (size_t)nt * 64;
    #pragma unroll
    for (int it = 0; it < 16; ++it){
        int f = it * 256 + t;
        int jj = f >> 6, ii = f & 63; // jj = o-local, ii = n-local
        size_t idx = obase + (size_t)jj * HW_N + ii;
        out[idx] = tile[ii][jj] + x[idx];
    }
}

// ---------------------------------------------------------------------------
extern "C" void kernel_launch(void* const* d_in, const int* in_sizes, int n_in,
                              void* d_out, int out_size, void* d_ws, size_t ws_size,
                              hipStream_t stream){
    const float* x     = (const float*)d_in[0];
    const float* w_qkv = (const float*)d_in[1];
    const float* b_qkv = (const float*)d_in[2];
    const float* kln_w = (const float*)d_in[3];
    const float* kln_b = (const float*)d_in[4];
    const float* vln_w = (const float*)d_in[5];
    const float* vln_b = (const float*)d_in[6];
    const float* w_o1  = (const float*)d_in[7];
    const float* b_o1  = (const float*)d_in[8];
    const float* w_o2  = (const float*)d_in[9];
    const float* b_o2  = (const float*)d_in[10];
    float* out = (float*)d_out;

    const size_t MB = 1u << 20;
    // workspace map (~266 MB):
    //   [0,64M)     xb      bf16 [B*N,256]
    //   [64M,192M)  kvraw   bf16 [B*N,512]; later y1b@64M, y2b@128M
    //   [192M,256M) kvpart  fp32 [B][64][8][1024] (16 MB) -> then ret_b bf16 (64 MB)
    //   [264M,..)   small: wkv_b, bkv_re, w_o1_b, w_o2_b, wq_eff_b, beff
    if (ws_size < 266 * MB) return;

    char* ws = (char*)d_ws;
    u16*   xb      = (u16*)(ws);
    u16*   kvraw   = (u16*)(ws + 64 * MB);
    u16*   y1b     = (u16*)(ws + 64 * MB);
    u16*   y2b     = (u16*)(ws + 128 * MB);
    float* kvpart  = (float*)(ws + 192 * MB);   // dead once k_wqeff ran
    u16*   ret_b   = (u16*)(ws + 192 * MB);     // written by K3 afterwards
    char*  sm      = ws + 264 * MB;
    u16*   wkv_b   = (u16*)sm;                       // 256KB
    float* bkv_re  = (float*)(sm + 256 * 1024);      // 2KB
    u16*   w_o1_b  = (u16*)(sm + 260 * 1024);        // 128KB
    u16*   w_o2_b  = (u16*)(sm + 392 * 1024);        // 128KB
    u16*   wq_effb = (u16*)(sm + 524 * 1024);        // 1MB
    float* beff    = (float*)(sm + 1572 * 1024);     // 8KB

    // K0a: transpose+cast x -> xb
    k_transpose_cast<<<dim3(HW_N / 64, CCH / 64, BATCH), 256, 0, stream>>>(x, xb);
    // K0b: weight prep
    k_weight_prep<<<dim3(1024), 256, 0, stream>>>(w_qkv, b_qkv, w_o1, w_o2,
                                                  wkv_b, bkv_re, w_o1_b, w_o2_b);
    // K1a: k/v projection GEMM -> kvraw [B*N, 512] (bias added pre-LN)
    k_gemm<false, false><<<dim3(4, 128, BATCH), 256, 0, stream>>>(
        xb, wkv_b, bkv_re, nullptr, kvraw, 512, HW_N, 0, 0);
    // K1b: LN + kv partial sums (MFMA)
    k_ln_kv<<<dim3(64, BATCH), 256, 0, stream>>>(kvraw, kln_w, kln_b, vln_w, vln_b, kvpart);
    // K2: reduce partials, build per-batch effective q-weights
    k_wqeff<<<dim3(NHEAD, BATCH), 256, 0, stream>>>(kvpart, w_qkv, b_qkv, wq_effb, beff);
    // K3: att = x @ wq_eff^T + beff ; ret = att + x   (per-batch Bt)
    k_gemm<false, true><<<dim3(2, 128, BATCH), 256, 0, stream>>>(
        xb, wq_effb, beff, xb, ret_b, 256, HW_N, 65536, 256);
    // K4: y1 = gelu(ret @ w_o1^T + b_o1)
    k_gemm<true, false><<<dim3(2, 128, BATCH), 256, 0, stream>>>(
        ret_b, w_o1_b, b_o1, nullptr, y1b, 256, HW_N, 0, 0);
    // K5: y2 = y1 @ w_o2^T + b_o2
    k_gemm<false, false><<<dim3(2, 128, BATCH), 256, 0, stream>>>(
        y1b, w_o2_b, b_o2, nullptr, y2b, 256, HW_N, 0, 0);
    // K6: out = y2^T + x
    k_out_trans<<<dim3(HW_N / 64, CCH / 64, BATCH), 256, 0, stream>>>(y2b, x, out);
}

// Round 3
// 305.336 us; speedup vs baseline: 1.8574x; 1.2113x over previous
//
#include <hip/hip_runtime.h>
#include <hip/hip_bf16.h>
#include <cstdint>

typedef unsigned short u16;
typedef __attribute__((ext_vector_type(8))) short short8;
typedef __attribute__((ext_vector_type(4))) short short4v;
typedef __attribute__((ext_vector_type(4))) float f32x4;

#define HW_N 16384   // H*W
#define CCH  256     // C
#define BATCH 8
#define NHEAD 8
#define HEADC 32

static __device__ __forceinline__ float bf2f(u16 u){
    union { float f; uint32_t i; } x; x.i = ((uint32_t)u) << 16; return x.f;
}
static __device__ __forceinline__ u16 f2bf(float f){
    union { float f; uint32_t i; } x; x.f = f;
    uint32_t r = x.i + 0x7fffu + ((x.i >> 16) & 1u);   // round-to-nearest-even
    return (u16)(r >> 16);
}

#define GLD16(gp, lp) __builtin_amdgcn_global_load_lds( \
    (const __attribute__((address_space(1))) uint32_t*)(gp), \
    (__attribute__((address_space(3))) uint32_t*)(lp), 16, 0, 0)

// ---------------------------------------------------------------------------
// K0a: x [B,C,N] fp32 -> xb [B*N, C] bf16  (transpose + cast, LDS-tiled)
// ---------------------------------------------------------------------------
__global__ __launch_bounds__(256) void k_transpose_cast(const float* __restrict__ x,
                                                        u16* __restrict__ xb){
    __shared__ float tile[64][65];
    int b = blockIdx.z, ct = blockIdx.y, nt = blockIdx.x;
    int t = threadIdx.x;
    const float* src = x + ((size_t)b * CCH + ct * 64) * HW_N + nt * 64;
    #pragma unroll
    for (int it = 0; it < 16; ++it){
        int f = it * 256 + t;
        int i = f >> 6, j = f & 63;              // i = c-local, j = n-local
        tile[i][j] = src[(size_t)i * HW_N + j];  // coalesced (j fastest)
    }
    __syncthreads();
    u16* dst = xb + ((size_t)b * HW_N + nt * 64) * CCH + ct * 64;
    #pragma unroll
    for (int it = 0; it < 16; ++it){
        int f = it * 256 + t;
        int jj = f >> 6, ii = f & 63;            // jj = n-local, ii = c-local
        dst[(size_t)jj * CCH + ii] = f2bf(tile[ii][jj]);  // coalesced writes
    }
}

// ---------------------------------------------------------------------------
// K0b: weight prep. wkv_b[h*64 + s*32 + d] <- w_qkv row (h*96 + 32 + s*32 + d)
// ---------------------------------------------------------------------------
__global__ __launch_bounds__(256) void k_weight_prep(const float* __restrict__ w_qkv,
                                                     const float* __restrict__ b_qkv,
                                                     const float* __restrict__ w_o1,
                                                     const float* __restrict__ w_o2,
                                                     u16* __restrict__ wkv_b,
                                                     float* __restrict__ bkv_re,
                                                     u16* __restrict__ w_o1_b,
                                                     u16* __restrict__ w_o2_b){
    int id = blockIdx.x * 256 + threadIdx.x;
    if (id < 512 * 256){
        int r = id >> 8, c = id & 255;
        int h = r >> 6, s = (r >> 5) & 1, d = r & 31;
        int srow = h * 96 + 32 + s * 32 + d;
        wkv_b[id] = f2bf(w_qkv[(size_t)srow * 256 + c]);
        if (c == 0) bkv_re[r] = b_qkv[srow];
    } else {
        int id2 = id - 512 * 256;
        if (id2 < 65536)       w_o1_b[id2]         = f2bf(w_o1[id2]);
        else if (id2 < 131072) w_o2_b[id2 - 65536] = f2bf(w_o2[id2 - 65536]);
    }
}

// ---------------------------------------------------------------------------
// Shared MFMA GEMM with coalesced LDS-transposed epilogue.
//   out[n,o] = bf16( act( acc + bias[o] (+ resid[n,o]) ) )          (!OUTF32)
//   outf[b,o,n] = acc + bias[o] + xres[b,o,n]                        (OUTF32)
// 128x128 tile, BK=64, 4 waves (2x2), 16x16x32 bf16 MFMA.
// Staging: global_load_lds w=16, XOR-swizzled source / swizzled ds_read_b128.
// Epilogue: acc -> bf16 packed ds_write_b64 into swizzled 32KB tile ->
//   uint4 read-back -> fully-coalesced 256B-per-row global stores.
// Block swizzle: gx siblings sharing an A-panel -> same XCD (lin mod 8).
// ---------------------------------------------------------------------------
template<bool GELU, bool RESID, bool OUTF32>
__global__ __launch_bounds__(256, 4) void k_gemm(const u16* __restrict__ A,
                                                 const u16* __restrict__ Bt0,
                                                 const float* __restrict__ bias0,
                                                 const u16* __restrict__ resid,
                                                 u16* __restrict__ out,
                                                 const float* __restrict__ xres,
                                                 float* __restrict__ outf,
                                                 int NC, int Mb,
                                                 long bt_stride, int bias_stride){
    __shared__ __align__(16) u16 sh[16384];     // 32 KB: lsA|lsB, then epilogue
    u16* lsA = sh;
    u16* lsB = sh + 8192;

    // ---- XCD sibling-grouping block swizzle (gridDim.y must be 128) ----
    int gx = gridDim.x;
    int lin = blockIdx.x + gx * (blockIdx.y + gridDim.y * blockIdx.z);
    int lg = (gx == 4) ? 2 : 1;                  // gx is 2 or 4
    int bx = (lin >> 3) & (gx - 1);
    int rest = (lin & 7) | ((lin >> (3 + lg)) << 3);
    int by = rest & 127;
    int bz = rest >> 7;

    int row0 = bz * Mb + by * 128;
    int col0 = bx * 128;
    const u16* Bt = Bt0 + (size_t)bz * bt_stride;
    const float* bias = bias0 + (size_t)bz * bias_stride;

    int t = threadIdx.x;
    int wid = t >> 6, lane = t & 63;
    int wr = wid >> 1, wc = wid & 1;     // 2x2 wave grid over 128x128 tile

    f32x4 acc[4][4];
    #pragma unroll
    for (int i = 0; i < 4; ++i)
        #pragma unroll
        for (int j = 0; j < 4; ++j) acc[i][j] = (f32x4)0.0f;

    for (int kt = 0; kt < 4; ++kt){
        int c0 = kt * 64;
        #pragma unroll
        for (int it = 0; it < 4; ++it){
            int f  = it * 256 + t;
            int fs = f ^ ((f >> 3) & 7);           // inverse-swizzle the source
            int r  = f >> 3, c8 = (fs & 7) * 8;
            GLD16(&A [((size_t)(row0 + r)) * 256 + c0 + c8], &lsA[f * 8]);
            GLD16(&Bt[((size_t)(col0 + r)) * 256 + c0 + c8], &lsB[f * 8]);
        }
        __syncthreads();
        int lrow = lane & 15;
        #pragma unroll
        for (int ks = 0; ks < 2; ++ks){
            int lk = (lane >> 4) * 8 + ks * 32;
            short8 af[4], bfr[4];
            #pragma unroll
            for (int mi = 0; mi < 4; ++mi){
                int row = wr * 64 + mi * 16 + lrow;
                int e = (row * 64 + lk) ^ ((row & 7) << 3);
                af[mi] = *(const short8*)&lsA[e];
            }
            #pragma unroll
            for (int ni = 0; ni < 4; ++ni){
                int row = wc * 64 + ni * 16 + lrow;
                int e = (row * 64 + lk) ^ ((row & 7) << 3);
                bfr[ni] = *(const short8*)&lsB[e];
            }
            // Operand order picks the D-fragment orientation so that each
            // lane's 4 regs are CONTIGUOUS in the LDS epilogue tile:
            //  !OUTF32: mfma(B,A): regs = 4 consecutive o at fixed n  ([n][o] tile)
            //   OUTF32: mfma(A,B): regs = 4 consecutive n at fixed o  ([o][n] tile)
            #pragma unroll
            for (int mi = 0; mi < 4; ++mi)
                #pragma unroll
                for (int ni = 0; ni < 4; ++ni)
                    acc[mi][ni] = OUTF32
                        ? __builtin_amdgcn_mfma_f32_16x16x32_bf16(af[mi], bfr[ni], acc[mi][ni], 0, 0, 0)
                        : __builtin_amdgcn_mfma_f32_16x16x32_bf16(bfr[ni], af[mi], acc[mi][ni], 0, 0, 0);
        }
        __syncthreads();   // also protects sh reuse by the epilogue
    }

    // ---- epilogue phase 1: packed bf16 ds_write_b64 into swizzled tile ----
    {
        int lrow = lane & 15, q4 = (lane >> 4) * 4;
        #pragma unroll
        for (int mi = 0; mi < 4; ++mi){
            #pragma unroll
            for (int ni = 0; ni < 4; ++ni){
                short4v pk;
                #pragma unroll
                for (int r = 0; r < 4; ++r) pk[r] = (short)f2bf(acc[mi][ni][r]);
                int byteoff;
                if (!OUTF32){
                    int nloc = wr * 64 + mi * 16 + lrow;      // D col = n
                    int oloc = wc * 64 + ni * 16 + q4;        // D rows = o (packed)
                    byteoff = (nloc << 8) + (oloc << 1);
                    byteoff ^= ((nloc ^ (nloc >> 2)) & 3) << 5;
                } else {
                    int oloc = wc * 64 + ni * 16 + lrow;      // D col = o
                    int nloc = wr * 64 + mi * 16 + q4;        // D rows = n (packed)
                    byteoff = (oloc << 8) + (nloc << 1);
                    byteoff ^= (oloc & 15) << 4;
                }
                *(short4v*)((char*)sh + byteoff) = pk;
            }
        }
    }
    __syncthreads();

    // ---- epilogue phase 2: coalesced read-back + bias/resid/gelu + store ----
    if (!OUTF32){
        #pragma unroll
        for (int it = 0; it < 8; ++it){
            int f = it * 256 + t;
            int row = f >> 4, cb = f & 15;               // row = n-local
            int byteoff = (row << 8) + ((cb << 4) ^ ((((row ^ (row >> 2)) & 3) << 5)));
            short8 av = *(const short8*)((char*)sh + byteoff);
            int gr = row0 + row;
            int gc = col0 + cb * 8;
            f32x4 bv0 = *(const f32x4*)&bias[gc];
            f32x4 bv1 = *(const f32x4*)&bias[gc + 4];
            float vv[8];
            #pragma unroll
            for (int j = 0; j < 4; ++j){ vv[j] = bf2f((u16)av[j]) + bv0[j];
                                         vv[j+4] = bf2f((u16)av[j+4]) + bv1[j]; }
            if (RESID){
                short8 rv = *(const short8*)&resid[(size_t)gr * NC + gc];
                #pragma unroll
                for (int j = 0; j < 8; ++j) vv[j] += bf2f((u16)rv[j]);
            }
            if (GELU){
                #pragma unroll
                for (int j = 0; j < 8; ++j)
                    vv[j] = 0.5f * vv[j] * (1.0f + erff(vv[j] * 0.70710678118654752f));
            }
            short8 pk;
            #pragma unroll
            for (int j = 0; j < 8; ++j) pk[j] = (short)f2bf(vv[j]);
            *(short8*)&out[(size_t)gr * NC + gc] = pk;
        }
    } else {
        #pragma unroll
        for (int it = 0; it < 8; ++it){
            int f = it * 256 + t;
            int o = f >> 4, nb = f & 15;
            int byteoff = (o << 8) + ((nb ^ (o & 15)) << 4);
            short8 av = *(const short8*)((char*)sh + byteoff);
            int go = col0 + o;                            // output channel
            size_t base = ((size_t)(bz * 256 + go)) * HW_N + by * 128 + nb * 8;
            float bo = bias[go];
            f32x4 x0 = *(const f32x4*)&xres[base];
            f32x4 x1 = *(const f32x4*)&xres[base + 4];
            f32x4 o0, o1;
            #pragma unroll
            for (int j = 0; j < 4; ++j){
                o0[j] = bf2f((u16)av[j])   + bo + x0[j];
                o1[j] = bf2f((u16)av[j+4]) + bo + x1[j];
            }
            *(f32x4*)&outf[base]     = o0;
            *(f32x4*)&outf[base + 4] = o1;
        }
    }
}

// ---------------------------------------------------------------------------
// K1b: per-head LN of k,v + kv partial via MFMA. (unchanged from round 1)
// ---------------------------------------------------------------------------
__global__ __launch_bounds__(256) void k_ln_kv(const u16* __restrict__ kvraw,
                                               const float* __restrict__ kln_w,
                                               const float* __restrict__ kln_b,
                                               const float* __restrict__ vln_w,
                                               const float* __restrict__ vln_b,
                                               float* __restrict__ kvpart){
    union ShU { u16 raw[128 * 72]; float pkv[4096]; };
    __shared__ __align__(16) ShU sh;
    __shared__ __align__(16) u16 lkt[32 * 264];
    __shared__ __align__(16) u16 lvt[32 * 264];

    int t = threadIdx.x, lane = t & 63, wid = t >> 6;
    int b = blockIdx.y, ch = blockIdx.x;          // ch: 0..63
    size_t nbase = (size_t)b * HW_N + (size_t)ch * 256;
    int s = t >> 7, nl = t & 127;                 // s: 0=k, 1=v
    const float* lnw = s ? vln_w : kln_w;
    const float* lnb = s ? vln_b : kln_b;
    u16* ldst = s ? lvt : lkt;

    for (int h = 0; h < 8; ++h){
        for (int sub = 0; sub < 2; ++sub){
            __syncthreads();
            #pragma unroll
            for (int it = 0; it < 4; ++it){
                int f = it * 256 + t;             // 0..1023
                int r = f >> 3, c = f & 7;
                const u16* g = kvraw + (nbase + sub * 128 + r) * 512 + h * 64 + c * 8;
                *(uint4*)&sh.raw[r * 72 + c * 8] = *(const uint4*)g;
            }
            __syncthreads();
            float xr[32];
            #pragma unroll
            for (int q = 0; q < 4; ++q){
                short8 v8 = *(const short8*)&sh.raw[nl * 72 + s * 32 + q * 8];
                #pragma unroll
                for (int j = 0; j < 8; ++j) xr[q * 8 + j] = bf2f((u16)v8[j]);
            }
            float mu = 0.f;
            #pragma unroll
            for (int d = 0; d < 32; ++d) mu += xr[d];
            mu *= (1.0f / 32.0f);
            float var = 0.f;
            #pragma unroll
            for (int d = 0; d < 32; ++d){ float dd = xr[d] - mu; var += dd * dd; }
            float rs = rsqrtf(var * (1.0f / 32.0f) + 1e-5f);
            #pragma unroll
            for (int d = 0; d < 32; ++d){
                float o = (xr[d] - mu) * rs * lnw[h * 32 + d] + lnb[h * 32 + d];
                ldst[d * 264 + sub * 128 + nl] = f2bf(o);
            }
        }
        __syncthreads();
        int lrow = lane & 15, g = lane >> 4;
        f32x4 acc[2][2];
        #pragma unroll
        for (int i = 0; i < 2; ++i)
            #pragma unroll
            for (int j = 0; j < 2; ++j) acc[i][j] = (f32x4)0.0f;
        #pragma unroll
        for (int ks = 0; ks < 2; ++ks){
            int col = wid * 64 + ks * 32 + g * 8;
            short8 af0 = *(const short8*)&lkt[lrow * 264 + col];
            short8 af1 = *(const short8*)&lkt[(16 + lrow) * 264 + col];
            short8 bf0 = *(const short8*)&lvt[lrow * 264 + col];
            short8 bf1 = *(const short8*)&lvt[(16 + lrow) * 264 + col];
            acc[0][0] = __builtin_amdgcn_mfma_f32_16x16x32_bf16(af0, bf0, acc[0][0], 0, 0, 0);
            acc[0][1] = __builtin_amdgcn_mfma_f32_16x16x32_bf16(af0, bf1, acc[0][1], 0, 0, 0);
            acc[1][0] = __builtin_amdgcn_mfma_f32_16x16x32_bf16(af1, bf0, acc[1][0], 0, 0, 0);
            acc[1][1] = __builtin_amdgcn_mfma_f32_16x16x32_bf16(af1, bf1, acc[1][1], 0, 0, 0);
        }
        #pragma unroll
        for (int mi = 0; mi < 2; ++mi)
            #pragma unroll
            for (int ni = 0; ni < 2; ++ni)
                #pragma unroll
                for (int r = 0; r < 4; ++r){
                    int d = mi * 16 + g * 4 + r, e = ni * 16 + lrow;
                    sh.pkv[wid * 1024 + d * 32 + e] = acc[mi][ni][r];
                }
        __syncthreads();
        f32x4 a0 = *(const f32x4*)&sh.pkv[t * 4];
        f32x4 a1 = *(const f32x4*)&sh.pkv[1024 + t * 4];
        f32x4 a2 = *(const f32x4*)&sh.pkv[2048 + t * 4];
        f32x4 a3 = *(const f32x4*)&sh.pkv[3072 + t * 4];
        f32x4 s4 = a0 + a1 + a2 + a3;
        *(f32x4*)(kvpart + (((size_t)b * 64 + ch) * 8 + h) * 1024 + t * 4) = s4;
    }
}

// ---------------------------------------------------------------------------
// K2: reduce kv partials (64 chunks), form wq_eff[b,h,e,c] and beff[b,h,e]
// ---------------------------------------------------------------------------
__global__ __launch_bounds__(256) void k_wqeff(const float* __restrict__ kvpart,
                                               const float* __restrict__ w_qkv,
                                               const float* __restrict__ b_qkv,
                                               u16* __restrict__ wq_eff_b,
                                               float* __restrict__ beff){
    __shared__ float kv[1024];   // [d*32 + e]
    int h = blockIdx.x, b = blockIdx.y;
    int t = threadIdx.x;
    f32x4 s = (f32x4)0.0f;
    for (int p = 0; p < 64; ++p){
        f32x4 v = *(const f32x4*)(kvpart + (((size_t)b * 64 + p) * 8 + h) * 1024 + t * 4);
        s = s + v;
    }
    const float invN = 1.0f / (float)HW_N;
    #pragma unroll
    for (int i = 0; i < 4; ++i) kv[t * 4 + i] = s[i] * invN;
    __syncthreads();

    float wcol[32];
    #pragma unroll
    for (int d = 0; d < 32; ++d)
        wcol[d] = w_qkv[((size_t)(h * 96 + d)) * 256 + t];   // q rows, coalesced
    for (int e = 0; e < 32; ++e){
        float s2 = 0.f;
        #pragma unroll
        for (int d = 0; d < 32; ++d) s2 += wcol[d] * kv[d * 32 + e];
        wq_eff_b[(((size_t)b * 256) + h * 32 + e) * 256 + t] = f2bf(s2);
    }
    if (t < 32){
        float s3 = 0.f;
        #pragma unroll
        for (int d = 0; d < 32; ++d) s3 += b_qkv[h * 96 + d] * kv[d * 32 + t];
        beff[b * 256 + h * 32 + t] = s3;
    }
}

// ---------------------------------------------------------------------------
extern "C" void kernel_launch(void* const* d_in, const int* in_sizes, int n_in,
                              void* d_out, int out_size, void* d_ws, size_t ws_size,
                              hipStream_t stream){
    const float* x     = (const float*)d_in[0];
    const float* w_qkv = (const float*)d_in[1];
    const float* b_qkv = (const float*)d_in[2];
    const float* kln_w = (const float*)d_in[3];
    const float* kln_b = (const float*)d_in[4];
    const float* vln_w = (const float*)d_in[5];
    const float* vln_b = (const float*)d_in[6];
    const float* w_o1  = (const float*)d_in[7];
    const float* b_o1  = (const float*)d_in[8];
    const float* w_o2  = (const float*)d_in[9];
    const float* b_o2  = (const float*)d_in[10];
    float* out = (float*)d_out;

    const size_t MB = 1u << 20;
    if (ws_size < 266 * MB) return;

    char* ws = (char*)d_ws;
    u16*   xb      = (u16*)(ws);
    u16*   kvraw   = (u16*)(ws + 64 * MB);
    u16*   y1b     = (u16*)(ws + 64 * MB);      // aliases kvraw (dead by K4)
    float* kvpart  = (float*)(ws + 192 * MB);   // dead once k_wqeff ran
    u16*   ret_b   = (u16*)(ws + 192 * MB);     // written by K3 afterwards
    char*  sm      = ws + 264 * MB;
    u16*   wkv_b   = (u16*)sm;                       // 256KB
    float* bkv_re  = (float*)(sm + 256 * 1024);      // 2KB
    u16*   w_o1_b  = (u16*)(sm + 260 * 1024);        // 128KB
    u16*   w_o2_b  = (u16*)(sm + 392 * 1024);        // 128KB
    u16*   wq_effb = (u16*)(sm + 524 * 1024);        // 1MB
    float* beff    = (float*)(sm + 1572 * 1024);     // 8KB

    // K0a: transpose+cast x -> xb
    k_transpose_cast<<<dim3(HW_N / 64, CCH / 64, BATCH), 256, 0, stream>>>(x, xb);
    // K0b: weight prep
    k_weight_prep<<<dim3(1024), 256, 0, stream>>>(w_qkv, b_qkv, w_o1, w_o2,
                                                  wkv_b, bkv_re, w_o1_b, w_o2_b);
    // K1a: k/v projection GEMM -> kvraw [B*N, 512] (bias added pre-LN)
    k_gemm<false, false, false><<<dim3(4, 128, BATCH), 256, 0, stream>>>(
        xb, wkv_b, bkv_re, nullptr, kvraw, nullptr, nullptr, 512, HW_N, 0, 0);
    // K1b: LN + kv partial sums (MFMA)
    k_ln_kv<<<dim3(64, BATCH), 256, 0, stream>>>(kvraw, kln_w, kln_b, vln_w, vln_b, kvpart);
    // K2: reduce partials, build per-batch effective q-weights
    k_wqeff<<<dim3(NHEAD, BATCH), 256, 0, stream>>>(kvpart, w_qkv, b_qkv, wq_effb, beff);
    // K3: att = x @ wq_eff^T + beff ; ret = att + x   (per-batch Bt)
    k_gemm<false, true, false><<<dim3(2, 128, BATCH), 256, 0, stream>>>(
        xb, wq_effb, beff, xb, ret_b, nullptr, nullptr, 256, HW_N, 65536, 256);
    // K4: y1 = gelu(ret @ w_o1^T + b_o1)
    k_gemm<true, false, false><<<dim3(2, 128, BATCH), 256, 0, stream>>>(
        ret_b, w_o1_b, b_o1, nullptr, y1b, nullptr, nullptr, 256, HW_N, 0, 0);
    // K5 (+K6 fused): out[b,o,n] = (y1 @ w_o2^T) + b_o2 + x   (fp32, transposed)
    k_gemm<false, false, true><<<dim3(2, 128, BATCH), 256, 0, stream>>>(
        y1b, w_o2_b, b_o2, nullptr, nullptr, x, out, 256, HW_N, 0, 0);
}

// Round 4
// 271.862 us; speedup vs baseline: 2.0861x; 1.1231x over previous
//
#include <hip/hip_runtime.h>
#include <hip/hip_bf16.h>
#include <cstdint>

typedef unsigned short u16;
typedef __attribute__((ext_vector_type(8))) short short8;
typedef __attribute__((ext_vector_type(4))) short short4v;
typedef __attribute__((ext_vector_type(4))) float f32x4;

#define HW_N 16384   // H*W
#define CCH  256     // C
#define BATCH 8
#define NHEAD 8
#define HEADC 32

static __device__ __forceinline__ float bf2f(u16 u){
    union { float f; uint32_t i; } x; x.i = ((uint32_t)u) << 16; return x.f;
}
static __device__ __forceinline__ u16 f2bf(float f){
    union { float f; uint32_t i; } x; x.f = f;
    uint32_t r = x.i + 0x7fffu + ((x.i >> 16) & 1u);   // round-to-nearest-even
    return (u16)(r >> 16);
}

#define GLD16(gp, lp) __builtin_amdgcn_global_load_lds( \
    (const __attribute__((address_space(1))) uint32_t*)(gp), \
    (__attribute__((address_space(3))) uint32_t*)(lp), 16, 0, 0)

// ---------------------------------------------------------------------------
// K0a: x [B,C,N] fp32 -> xb [B*N, C] bf16  (transpose + cast, LDS-tiled)
// ---------------------------------------------------------------------------
__global__ __launch_bounds__(256) void k_transpose_cast(const float* __restrict__ x,
                                                        u16* __restrict__ xb){
    __shared__ float tile[64][65];
    int b = blockIdx.z, ct = blockIdx.y, nt = blockIdx.x;
    int t = threadIdx.x;
    const float* src = x + ((size_t)b * CCH + ct * 64) * HW_N + nt * 64;
    #pragma unroll
    for (int it = 0; it < 16; ++it){
        int f = it * 256 + t;
        int i = f >> 6, j = f & 63;              // i = c-local, j = n-local
        tile[i][j] = src[(size_t)i * HW_N + j];  // coalesced (j fastest)
    }
    __syncthreads();
    u16* dst = xb + ((size_t)b * HW_N + nt * 64) * CCH + ct * 64;
    #pragma unroll
    for (int it = 0; it < 16; ++it){
        int f = it * 256 + t;
        int jj = f >> 6, ii = f & 63;            // jj = n-local, ii = c-local
        dst[(size_t)jj * CCH + ii] = f2bf(tile[ii][jj]);  // coalesced writes
    }
}

// ---------------------------------------------------------------------------
// K0b: weight prep. wkv_b[h*64 + s*32 + d] <- w_qkv row (h*96 + 32 + s*32 + d)
// ---------------------------------------------------------------------------
__global__ __launch_bounds__(256) void k_weight_prep(const float* __restrict__ w_qkv,
                                                     const float* __restrict__ b_qkv,
                                                     const float* __restrict__ w_o1,
                                                     const float* __restrict__ w_o2,
                                                     u16* __restrict__ wkv_b,
                                                     float* __restrict__ bkv_re,
                                                     u16* __restrict__ w_o1_b,
                                                     u16* __restrict__ w_o2_b){
    int id = blockIdx.x * 256 + threadIdx.x;
    if (id < 512 * 256){
        int r = id >> 8, c = id & 255;
        int h = r >> 6, s = (r >> 5) & 1, d = r & 31;
        int srow = h * 96 + 32 + s * 32 + d;
        wkv_b[id] = f2bf(w_qkv[(size_t)srow * 256 + c]);
        if (c == 0) bkv_re[r] = b_qkv[srow];
    } else {
        int id2 = id - 512 * 256;
        if (id2 < 65536)       w_o1_b[id2]         = f2bf(w_o1[id2]);
        else if (id2 < 131072) w_o2_b[id2 - 65536] = f2bf(w_o2[id2 - 65536]);
    }
}

// ---------------------------------------------------------------------------
// Shared MFMA GEMM with coalesced LDS-transposed epilogue. (unchanged, round 3)
// ---------------------------------------------------------------------------
template<bool GELU, bool RESID, bool OUTF32>
__global__ __launch_bounds__(256, 4) void k_gemm(const u16* __restrict__ A,
                                                 const u16* __restrict__ Bt0,
                                                 const float* __restrict__ bias0,
                                                 const u16* __restrict__ resid,
                                                 u16* __restrict__ out,
                                                 const float* __restrict__ xres,
                                                 float* __restrict__ outf,
                                                 int NC, int Mb,
                                                 long bt_stride, int bias_stride){
    __shared__ __align__(16) u16 sh[16384];     // 32 KB: lsA|lsB, then epilogue
    u16* lsA = sh;
    u16* lsB = sh + 8192;

    int gx = gridDim.x;
    int lin = blockIdx.x + gx * (blockIdx.y + gridDim.y * blockIdx.z);
    int lg = (gx == 4) ? 2 : 1;                  // gx is 2 or 4
    int bx = (lin >> 3) & (gx - 1);
    int rest = (lin & 7) | ((lin >> (3 + lg)) << 3);
    int by = rest & 127;
    int bz = rest >> 7;

    int row0 = bz * Mb + by * 128;
    int col0 = bx * 128;
    const u16* Bt = Bt0 + (size_t)bz * bt_stride;
    const float* bias = bias0 + (size_t)bz * bias_stride;

    int t = threadIdx.x;
    int wid = t >> 6, lane = t & 63;
    int wr = wid >> 1, wc = wid & 1;     // 2x2 wave grid over 128x128 tile

    f32x4 acc[4][4];
    #pragma unroll
    for (int i = 0; i < 4; ++i)
        #pragma unroll
        for (int j = 0; j < 4; ++j) acc[i][j] = (f32x4)0.0f;

    for (int kt = 0; kt < 4; ++kt){
        int c0 = kt * 64;
        #pragma unroll
        for (int it = 0; it < 4; ++it){
            int f  = it * 256 + t;
            int fs = f ^ ((f >> 3) & 7);           // inverse-swizzle the source
            int r  = f >> 3, c8 = (fs & 7) * 8;
            GLD16(&A [((size_t)(row0 + r)) * 256 + c0 + c8], &lsA[f * 8]);
            GLD16(&Bt[((size_t)(col0 + r)) * 256 + c0 + c8], &lsB[f * 8]);
        }
        __syncthreads();
        int lrow = lane & 15;
        #pragma unroll
        for (int ks = 0; ks < 2; ++ks){
            int lk = (lane >> 4) * 8 + ks * 32;
            short8 af[4], bfr[4];
            #pragma unroll
            for (int mi = 0; mi < 4; ++mi){
                int row = wr * 64 + mi * 16 + lrow;
                int e = (row * 64 + lk) ^ ((row & 7) << 3);
                af[mi] = *(const short8*)&lsA[e];
            }
            #pragma unroll
            for (int ni = 0; ni < 4; ++ni){
                int row = wc * 64 + ni * 16 + lrow;
                int e = (row * 64 + lk) ^ ((row & 7) << 3);
                bfr[ni] = *(const short8*)&lsB[e];
            }
            #pragma unroll
            for (int mi = 0; mi < 4; ++mi)
                #pragma unroll
                for (int ni = 0; ni < 4; ++ni)
                    acc[mi][ni] = OUTF32
                        ? __builtin_amdgcn_mfma_f32_16x16x32_bf16(af[mi], bfr[ni], acc[mi][ni], 0, 0, 0)
                        : __builtin_amdgcn_mfma_f32_16x16x32_bf16(bfr[ni], af[mi], acc[mi][ni], 0, 0, 0);
        }
        __syncthreads();   // also protects sh reuse by the epilogue
    }

    // ---- epilogue phase 1: packed bf16 ds_write_b64 into swizzled tile ----
    {
        int lrow = lane & 15, q4 = (lane >> 4) * 4;
        #pragma unroll
        for (int mi = 0; mi < 4; ++mi){
            #pragma unroll
            for (int ni = 0; ni < 4; ++ni){
                short4v pk;
                #pragma unroll
                for (int r = 0; r < 4; ++r) pk[r] = (short)f2bf(acc[mi][ni][r]);
                int byteoff;
                if (!OUTF32){
                    int nloc = wr * 64 + mi * 16 + lrow;      // D col = n
                    int oloc = wc * 64 + ni * 16 + q4;        // D rows = o (packed)
                    byteoff = (nloc << 8) + (oloc << 1);
                    byteoff ^= ((nloc ^ (nloc >> 2)) & 3) << 5;
                } else {
                    int oloc = wc * 64 + ni * 16 + lrow;      // D col = o
                    int nloc = wr * 64 + mi * 16 + q4;        // D rows = n (packed)
                    byteoff = (oloc << 8) + (nloc << 1);
                    byteoff ^= (oloc & 15) << 4;
                }
                *(short4v*)((char*)sh + byteoff) = pk;
            }
        }
    }
    __syncthreads();

    // ---- epilogue phase 2: coalesced read-back + bias/resid/gelu + store ----
    if (!OUTF32){
        #pragma unroll
        for (int it = 0; it < 8; ++it){
            int f = it * 256 + t;
            int row = f >> 4, cb = f & 15;               // row = n-local
            int byteoff = (row << 8) + ((cb << 4) ^ ((((row ^ (row >> 2)) & 3) << 5)));
            short8 av = *(const short8*)((char*)sh + byteoff);
            int gr = row0 + row;
            int gc = col0 + cb * 8;
            f32x4 bv0 = *(const f32x4*)&bias[gc];
            f32x4 bv1 = *(const f32x4*)&bias[gc + 4];
            float vv[8];
            #pragma unroll
            for (int j = 0; j < 4; ++j){ vv[j] = bf2f((u16)av[j]) + bv0[j];
                                         vv[j+4] = bf2f((u16)av[j+4]) + bv1[j]; }
            if (RESID){
                short8 rv = *(const short8*)&resid[(size_t)gr * NC + gc];
                #pragma unroll
                for (int j = 0; j < 8; ++j) vv[j] += bf2f((u16)rv[j]);
            }
            if (GELU){
                #pragma unroll
                for (int j = 0; j < 8; ++j)
                    vv[j] = 0.5f * vv[j] * (1.0f + erff(vv[j] * 0.70710678118654752f));
            }
            short8 pk;
            #pragma unroll
            for (int j = 0; j < 8; ++j) pk[j] = (short)f2bf(vv[j]);
            *(short8*)&out[(size_t)gr * NC + gc] = pk;
        }
    } else {
        #pragma unroll
        for (int it = 0; it < 8; ++it){
            int f = it * 256 + t;
            int o = f >> 4, nb = f & 15;
            int byteoff = (o << 8) + ((nb ^ (o & 15)) << 4);
            short8 av = *(const short8*)((char*)sh + byteoff);
            int go = col0 + o;                            // output channel
            size_t base = ((size_t)(bz * 256 + go)) * HW_N + by * 128 + nb * 8;
            float bo = bias[go];
            f32x4 x0 = *(const f32x4*)&xres[base];
            f32x4 x1 = *(const f32x4*)&xres[base + 4];
            f32x4 o0, o1;
            #pragma unroll
            for (int j = 0; j < 4; ++j){
                o0[j] = bf2f((u16)av[j])   + bo + x0[j];
                o1[j] = bf2f((u16)av[j+4]) + bo + x1[j];
            }
            *(f32x4*)&outf[base]     = o0;
            *(f32x4*)&outf[base + 4] = o1;
        }
    }
}

// ---------------------------------------------------------------------------
// K1 fused: kv-projection GEMM + per-head LN(k),LN(v) + kv partial reduce.
// Grid (4, 128, B); block covers 128 n-rows x 128 cols = heads {2bx, 2bx+1}.
// Per wave (wr,wc): 64 cols = head (2bx+wc): k = ni 0,1 ; v = ni 2,3.
// Swapped-MFMA D layout: o = wc*64+ni*16+q4+r, n = wr*64+mi*16+lrow
//   -> per (mi): lane holds 8 k + 8 v values of ONE row n -> LN stats via
//      shfl_xor(16/32). LN'd bf16 goes into the freed staging LDS as
//      4 x [32 d][128 n] tiles (byte ^= (d&7)<<4 swizzle), then waves 0/1
//      run mfma(k,v) 32x32xK=128 and store 1024-float partials to kvpart.
// ---------------------------------------------------------------------------
__global__ __launch_bounds__(256, 2) void k_gemm_kv(const u16* __restrict__ A,
                                                    const u16* __restrict__ Bt,
                                                    const float* __restrict__ bkv,
                                                    const float* __restrict__ kln_w,
                                                    const float* __restrict__ kln_b,
                                                    const float* __restrict__ vln_w,
                                                    const float* __restrict__ vln_b,
                                                    float* __restrict__ kvpart){
    __shared__ __align__(16) u16 sh[16384];     // staging, then LN'd k/v tiles
    u16* lsA = sh;
    u16* lsB = sh + 8192;

    // XCD sibling-grouping swizzle (gx=4, gy=128, gz=8), bijective
    int lin = blockIdx.x + 4 * (blockIdx.y + 128 * blockIdx.z);
    int bx = (lin >> 3) & 3;
    int rest = (lin & 7) | ((lin >> 5) << 3);
    int by = rest & 127;
    int bz = rest >> 7;

    int row0 = bz * HW_N + by * 128;
    int col0 = bx * 128;

    int t = threadIdx.x;
    int wid = t >> 6, lane = t & 63;
    int wr = wid >> 1, wc = wid & 1;
    int q = lane >> 4, q4 = q * 4, lrow = lane & 15;

    f32x4 acc[4][4];
    #pragma unroll
    for (int i = 0; i < 4; ++i)
        #pragma unroll
        for (int j = 0; j < 4; ++j) acc[i][j] = (f32x4)0.0f;

    for (int kt = 0; kt < 4; ++kt){
        int c0 = kt * 64;
        #pragma unroll
        for (int it = 0; it < 4; ++it){
            int f  = it * 256 + t;
            int fs = f ^ ((f >> 3) & 7);
            int r  = f >> 3, c8 = (fs & 7) * 8;
            GLD16(&A [((size_t)(row0 + r)) * 256 + c0 + c8], &lsA[f * 8]);
            GLD16(&Bt[((size_t)(col0 + r)) * 256 + c0 + c8], &lsB[f * 8]);
        }
        __syncthreads();
        #pragma unroll
        for (int ks = 0; ks < 2; ++ks){
            int lk = q * 8 + ks * 32;
            short8 af[4], bfr[4];
            #pragma unroll
            for (int mi = 0; mi < 4; ++mi){
                int row = wr * 64 + mi * 16 + lrow;
                int e = (row * 64 + lk) ^ ((row & 7) << 3);
                af[mi] = *(const short8*)&lsA[e];
            }
            #pragma unroll
            for (int ni = 0; ni < 4; ++ni){
                int row = wc * 64 + ni * 16 + lrow;
                int e = (row * 64 + lk) ^ ((row & 7) << 3);
                bfr[ni] = *(const short8*)&lsB[e];
            }
            #pragma unroll
            for (int mi = 0; mi < 4; ++mi)
                #pragma unroll
                for (int ni = 0; ni < 4; ++ni)
                    acc[mi][ni] = __builtin_amdgcn_mfma_f32_16x16x32_bf16(
                        bfr[ni], af[mi], acc[mi][ni], 0, 0, 0);   // swapped
        }
        __syncthreads();   // last iter: frees sh for the LN tiles
    }

    // ---- LN params / bias for this lane's 16 o-columns ----
    int h = 2 * bx + wc;
    float bv[4][4], lwv[4][4], lbv[4][4];
    #pragma unroll
    for (int ni = 0; ni < 4; ++ni){
        const float* w  = (ni < 2) ? kln_w : vln_w;
        const float* bb = (ni < 2) ? kln_b : vln_b;
        #pragma unroll
        for (int r = 0; r < 4; ++r){
            int de = (ni & 1) * 16 + q4 + r;          // channel within head
            bv[ni][r]  = bkv[col0 + wc * 64 + ni * 16 + q4 + r];
            lwv[ni][r] = w[h * 32 + de];
            lbv[ni][r] = bb[h * 32 + de];
        }
    }

    // ---- per-row LN (bias added pre-stats), write LN'd bf16 tiles ----
    #pragma unroll
    for (int mi = 0; mi < 4; ++mi){
        float ks = 0.f, ksq = 0.f, vs = 0.f, vsq = 0.f;
        #pragma unroll
        for (int ni = 0; ni < 4; ++ni)
            #pragma unroll
            for (int r = 0; r < 4; ++r){
                float t2 = acc[mi][ni][r] + bv[ni][r];
                acc[mi][ni][r] = t2;
                if (ni < 2){ ks += t2; ksq += t2 * t2; }
                else       { vs += t2; vsq += t2 * t2; }
            }
        ks  += __shfl_xor(ks, 16);  ks  += __shfl_xor(ks, 32);
        ksq += __shfl_xor(ksq, 16); ksq += __shfl_xor(ksq, 32);
        vs  += __shfl_xor(vs, 16);  vs  += __shfl_xor(vs, 32);
        vsq += __shfl_xor(vsq, 16); vsq += __shfl_xor(vsq, 32);
        float muk = ks * 0.03125f, muv = vs * 0.03125f;
        float rsk = rsqrtf(fmaxf(ksq * 0.03125f - muk * muk, 0.f) + 1e-5f);
        float rsv = rsqrtf(fmaxf(vsq * 0.03125f - muv * muv, 0.f) + 1e-5f);
        int n = wr * 64 + mi * 16 + lrow;
        #pragma unroll
        for (int ni = 0; ni < 4; ++ni){
            float mu = (ni < 2) ? muk : muv;
            float rs = (ni < 2) ? rsk : rsv;
            #pragma unroll
            for (int r = 0; r < 4; ++r){
                int d = (ni & 1) * 16 + q4 + r;
                float val = (acc[mi][ni][r] - mu) * rs * lwv[ni][r] + lbv[ni][r];
                int byteoff = ((wc * 2 + (ni >> 1)) << 13) + (d << 8) + (n << 1);
                byteoff ^= (d & 7) << 4;
                *(u16*)((char*)sh + byteoff) = f2bf(val);
            }
        }
    }
    __syncthreads();

    // ---- kv partial: waves 0,1 compute head (2bx+wid), K = 128 rows ----
    if (wid < 2){
        f32x4 a2[2][2];
        #pragma unroll
        for (int i = 0; i < 2; ++i)
            #pragma unroll
            for (int j = 0; j < 2; ++j) a2[i][j] = (f32x4)0.0f;
        #pragma unroll
        for (int ks2 = 0; ks2 < 4; ++ks2){
            int n0 = q * 8 + ks2 * 32;
            short8 kf[2], vf[2];
            #pragma unroll
            for (int mi = 0; mi < 2; ++mi){
                int d = mi * 16 + lrow;
                int bko = ((wid * 2 + 0) << 13) + (d << 8) + (n0 << 1);
                int bvo = ((wid * 2 + 1) << 13) + (d << 8) + (n0 << 1);
                bko ^= (d & 7) << 4;
                bvo ^= (d & 7) << 4;
                kf[mi] = *(const short8*)((char*)sh + bko);
                vf[mi] = *(const short8*)((char*)sh + bvo);
            }
            #pragma unroll
            for (int mi = 0; mi < 2; ++mi)
                #pragma unroll
                for (int ni = 0; ni < 2; ++ni)
                    a2[mi][ni] = __builtin_amdgcn_mfma_f32_16x16x32_bf16(
                        kf[mi], vf[ni], a2[mi][ni], 0, 0, 0);
        }
        float* dst = kvpart + (((size_t)(bz * 128 + by)) * 8 + 2 * bx + wid) * 1024;
        #pragma unroll
        for (int mi = 0; mi < 2; ++mi)
            #pragma unroll
            for (int ni = 0; ni < 2; ++ni)
                #pragma unroll
                for (int r = 0; r < 4; ++r)
                    dst[(mi * 16 + q4 + r) * 32 + ni * 16 + lrow] = a2[mi][ni][r];
    }
}

// ---------------------------------------------------------------------------
// K2: reduce kv partials (128 chunks), form wq_eff[b,h,e,c] and beff[b,h,e]
// ---------------------------------------------------------------------------
__global__ __launch_bounds__(256) void k_wqeff(const float* __restrict__ kvpart,
                                               const float* __restrict__ w_qkv,
                                               const float* __restrict__ b_qkv,
                                               u16* __restrict__ wq_eff_b,
                                               float* __restrict__ beff){
    __shared__ float kv[1024];   // [d*32 + e]
    int h = blockIdx.x, b = blockIdx.y;
    int t = threadIdx.x;
    f32x4 s = (f32x4)0.0f;
    for (int p = 0; p < 128; ++p){
        f32x4 v = *(const f32x4*)(kvpart + (((size_t)b * 128 + p) * 8 + h) * 1024 + t * 4);
        s = s + v;
    }
    const float invN = 1.0f / (float)HW_N;
    #pragma unroll
    for (int i = 0; i < 4; ++i) kv[t * 4 + i] = s[i] * invN;
    __syncthreads();

    float wcol[32];
    #pragma unroll
    for (int d = 0; d < 32; ++d)
        wcol[d] = w_qkv[((size_t)(h * 96 + d)) * 256 + t];   // q rows, coalesced
    for (int e = 0; e < 32; ++e){
        float s2 = 0.f;
        #pragma unroll
        for (int d = 0; d < 32; ++d) s2 += wcol[d] * kv[d * 32 + e];
        wq_eff_b[(((size_t)b * 256) + h * 32 + e) * 256 + t] = f2bf(s2);
    }
    if (t < 32){
        float s3 = 0.f;
        #pragma unroll
        for (int d = 0; d < 32; ++d) s3 += b_qkv[h * 96 + d] * kv[d * 32 + t];
        beff[b * 256 + h * 32 + t] = s3;
    }
}

// ---------------------------------------------------------------------------
extern "C" void kernel_launch(void* const* d_in, const int* in_sizes, int n_in,
                              void* d_out, int out_size, void* d_ws, size_t ws_size,
                              hipStream_t stream){
    const float* x     = (const float*)d_in[0];
    const float* w_qkv = (const float*)d_in[1];
    const float* b_qkv = (const float*)d_in[2];
    const float* kln_w = (const float*)d_in[3];
    const float* kln_b = (const float*)d_in[4];
    const float* vln_w = (const float*)d_in[5];
    const float* vln_b = (const float*)d_in[6];
    const float* w_o1  = (const float*)d_in[7];
    const float* b_o1  = (const float*)d_in[8];
    const float* w_o2  = (const float*)d_in[9];
    const float* b_o2  = (const float*)d_in[10];
    float* out = (float*)d_out;

    const size_t MB = 1u << 20;
    if (ws_size < 266 * MB) return;

    char* ws = (char*)d_ws;
    u16*   xb      = (u16*)(ws);
    u16*   y1b     = (u16*)(ws + 64 * MB);      // 64 MB
    float* kvpart  = (float*)(ws + 192 * MB);   // 32 MB, dead after k_wqeff
    u16*   ret_b   = (u16*)(ws + 192 * MB);     // written by K3 afterwards
    char*  sm      = ws + 264 * MB;
    u16*   wkv_b   = (u16*)sm;                       // 256KB
    float* bkv_re  = (float*)(sm + 256 * 1024);      // 2KB
    u16*   w_o1_b  = (u16*)(sm + 260 * 1024);        // 128KB
    u16*   w_o2_b  = (u16*)(sm + 392 * 1024);        // 128KB
    u16*   wq_effb = (u16*)(sm + 524 * 1024);        // 1MB
    float* beff    = (float*)(sm + 1572 * 1024);     // 8KB

    // K0a: transpose+cast x -> xb
    k_transpose_cast<<<dim3(HW_N / 64, CCH / 64, BATCH), 256, 0, stream>>>(x, xb);
    // K0b: weight prep
    k_weight_prep<<<dim3(1024), 256, 0, stream>>>(w_qkv, b_qkv, w_o1, w_o2,
                                                  wkv_b, bkv_re, w_o1_b, w_o2_b);
    // K1 fused: k/v projection + LN + kv partial sums (no kvraw round trip)
    k_gemm_kv<<<dim3(4, 128, BATCH), 256, 0, stream>>>(
        xb, wkv_b, bkv_re, kln_w, kln_b, vln_w, vln_b, kvpart);
    // K2: reduce partials, build per-batch effective q-weights
    k_wqeff<<<dim3(NHEAD, BATCH), 256, 0, stream>>>(kvpart, w_qkv, b_qkv, wq_effb, beff);
    // K3: att = x @ wq_eff^T + beff ; ret = att + x   (per-batch Bt)
    k_gemm<false, true, false><<<dim3(2, 128, BATCH), 256, 0, stream>>>(
        xb, wq_effb, beff, xb, ret_b, nullptr, nullptr, 256, HW_N, 65536, 256);
    // K4: y1 = gelu(ret @ w_o1^T + b_o1)
    k_gemm<true, false, false><<<dim3(2, 128, BATCH), 256, 0, stream>>>(
        ret_b, w_o1_b, b_o1, nullptr, y1b, nullptr, nullptr, 256, HW_N, 0, 0);
    // K5 (+K6 fused): out[b,o,n] = (y1 @ w_o2^T) + b_o2 + x   (fp32, transposed)
    k_gemm<false, false, true><<<dim3(2, 128, BATCH), 256, 0, stream>>>(
        y1b, w_o2_b, b_o2, nullptr, nullptr, x, out, 256, HW_N, 0, 0);
}

// Round 5
// 250.473 us; speedup vs baseline: 2.2642x; 1.0854x over previous
//
#include <hip/hip_runtime.h>
#include <hip/hip_bf16.h>
#include <cstdint>

typedef unsigned short u16;
typedef __attribute__((ext_vector_type(8))) short short8;
typedef __attribute__((ext_vector_type(4))) short short4v;
typedef __attribute__((ext_vector_type(4))) float f32x4;

#define HW_N 16384   // H*W
#define CCH  256     // C
#define BATCH 8
#define NHEAD 8
#define HEADC 32

static __device__ __forceinline__ float bf2f(u16 u){
    union { float f; uint32_t i; } x; x.i = ((uint32_t)u) << 16; return x.f;
}
static __device__ __forceinline__ u16 f2bf(float f){
    union { float f; uint32_t i; } x; x.f = f;
    uint32_t r = x.i + 0x7fffu + ((x.i >> 16) & 1u);   // round-to-nearest-even
    return (u16)(r >> 16);
}

#define GLD16(gp, lp) __builtin_amdgcn_global_load_lds( \
    (const __attribute__((address_space(1))) uint32_t*)(gp), \
    (__attribute__((address_space(3))) uint32_t*)(lp), 16, 0, 0)

// ---------------------------------------------------------------------------
// K0a: x [B,C,N] fp32 -> xb [B*N, C] bf16  (transpose + cast, LDS-tiled)
// ---------------------------------------------------------------------------
__global__ __launch_bounds__(256) void k_transpose_cast(const float* __restrict__ x,
                                                        u16* __restrict__ xb){
    __shared__ float tile[64][65];
    int b = blockIdx.z, ct = blockIdx.y, nt = blockIdx.x;
    int t = threadIdx.x;
    const float* src = x + ((size_t)b * CCH + ct * 64) * HW_N + nt * 64;
    #pragma unroll
    for (int it = 0; it < 16; ++it){
        int f = it * 256 + t;
        int i = f >> 6, j = f & 63;              // i = c-local, j = n-local
        tile[i][j] = src[(size_t)i * HW_N + j];  // coalesced (j fastest)
    }
    __syncthreads();
    u16* dst = xb + ((size_t)b * HW_N + nt * 64) * CCH + ct * 64;
    #pragma unroll
    for (int it = 0; it < 16; ++it){
        int f = it * 256 + t;
        int jj = f >> 6, ii = f & 63;            // jj = n-local, ii = c-local
        dst[(size_t)jj * CCH + ii] = f2bf(tile[ii][jj]);  // coalesced writes
    }
}

// ---------------------------------------------------------------------------
// K0b: weight prep. wkv_b[h*64 + s*32 + d] <- w_qkv row (h*96 + 32 + s*32 + d)
// ---------------------------------------------------------------------------
__global__ __launch_bounds__(256) void k_weight_prep(const float* __restrict__ w_qkv,
                                                     const float* __restrict__ b_qkv,
                                                     const float* __restrict__ w_o1,
                                                     const float* __restrict__ w_o2,
                                                     u16* __restrict__ wkv_b,
                                                     float* __restrict__ bkv_re,
                                                     u16* __restrict__ w_o1_b,
                                                     u16* __restrict__ w_o2_b){
    int id = blockIdx.x * 256 + threadIdx.x;
    if (id < 512 * 256){
        int r = id >> 8, c = id & 255;
        int h = r >> 6, s = (r >> 5) & 1, d = r & 31;
        int srow = h * 96 + 32 + s * 32 + d;
        wkv_b[id] = f2bf(w_qkv[(size_t)srow * 256 + c]);
        if (c == 0) bkv_re[r] = b_qkv[srow];
    } else {
        int id2 = id - 512 * 256;
        if (id2 < 65536)       w_o1_b[id2]         = f2bf(w_o1[id2]);
        else if (id2 < 131072) w_o2_b[id2 - 65536] = f2bf(w_o2[id2 - 65536]);
    }
}

// ---------------------------------------------------------------------------
// K1 fused: kv-projection GEMM + per-head LN(k),LN(v) + kv partial reduce.
// (unchanged from round 3)
// ---------------------------------------------------------------------------
__global__ __launch_bounds__(256, 2) void k_gemm_kv(const u16* __restrict__ A,
                                                    const u16* __restrict__ Bt,
                                                    const float* __restrict__ bkv,
                                                    const float* __restrict__ kln_w,
                                                    const float* __restrict__ kln_b,
                                                    const float* __restrict__ vln_w,
                                                    const float* __restrict__ vln_b,
                                                    float* __restrict__ kvpart){
    __shared__ __align__(16) u16 sh[16384];     // staging, then LN'd k/v tiles
    u16* lsA = sh;
    u16* lsB = sh + 8192;

    int lin = blockIdx.x + 4 * (blockIdx.y + 128 * blockIdx.z);
    int bx = (lin >> 3) & 3;
    int rest = (lin & 7) | ((lin >> 5) << 3);
    int by = rest & 127;
    int bz = rest >> 7;

    int row0 = bz * HW_N + by * 128;
    int col0 = bx * 128;

    int t = threadIdx.x;
    int wid = t >> 6, lane = t & 63;
    int wr = wid >> 1, wc = wid & 1;
    int q = lane >> 4, q4 = q * 4, lrow = lane & 15;

    f32x4 acc[4][4];
    #pragma unroll
    for (int i = 0; i < 4; ++i)
        #pragma unroll
        for (int j = 0; j < 4; ++j) acc[i][j] = (f32x4)0.0f;

    for (int kt = 0; kt < 4; ++kt){
        int c0 = kt * 64;
        #pragma unroll
        for (int it = 0; it < 4; ++it){
            int f  = it * 256 + t;
            int fs = f ^ ((f >> 3) & 7);
            int r  = f >> 3, c8 = (fs & 7) * 8;
            GLD16(&A [((size_t)(row0 + r)) * 256 + c0 + c8], &lsA[f * 8]);
            GLD16(&Bt[((size_t)(col0 + r)) * 256 + c0 + c8], &lsB[f * 8]);
        }
        __syncthreads();
        #pragma unroll
        for (int ks = 0; ks < 2; ++ks){
            int lk = q * 8 + ks * 32;
            short8 af[4], bfr[4];
            #pragma unroll
            for (int mi = 0; mi < 4; ++mi){
                int row = wr * 64 + mi * 16 + lrow;
                int e = (row * 64 + lk) ^ ((row & 7) << 3);
                af[mi] = *(const short8*)&lsA[e];
            }
            #pragma unroll
            for (int ni = 0; ni < 4; ++ni){
                int row = wc * 64 + ni * 16 + lrow;
                int e = (row * 64 + lk) ^ ((row & 7) << 3);
                bfr[ni] = *(const short8*)&lsB[e];
            }
            #pragma unroll
            for (int mi = 0; mi < 4; ++mi)
                #pragma unroll
                for (int ni = 0; ni < 4; ++ni)
                    acc[mi][ni] = __builtin_amdgcn_mfma_f32_16x16x32_bf16(
                        bfr[ni], af[mi], acc[mi][ni], 0, 0, 0);   // swapped
        }
        __syncthreads();
    }

    int h = 2 * bx + wc;
    float bv[4][4], lwv[4][4], lbv[4][4];
    #pragma unroll
    for (int ni = 0; ni < 4; ++ni){
        const float* w  = (ni < 2) ? kln_w : vln_w;
        const float* bb = (ni < 2) ? kln_b : vln_b;
        #pragma unroll
        for (int r = 0; r < 4; ++r){
            int de = (ni & 1) * 16 + q4 + r;
            bv[ni][r]  = bkv[col0 + wc * 64 + ni * 16 + q4 + r];
            lwv[ni][r] = w[h * 32 + de];
            lbv[ni][r] = bb[h * 32 + de];
        }
    }

    #pragma unroll
    for (int mi = 0; mi < 4; ++mi){
        float ks = 0.f, ksq = 0.f, vs = 0.f, vsq = 0.f;
        #pragma unroll
        for (int ni = 0; ni < 4; ++ni)
            #pragma unroll
            for (int r = 0; r < 4; ++r){
                float t2 = acc[mi][ni][r] + bv[ni][r];
                acc[mi][ni][r] = t2;
                if (ni < 2){ ks += t2; ksq += t2 * t2; }
                else       { vs += t2; vsq += t2 * t2; }
            }
        ks  += __shfl_xor(ks, 16);  ks  += __shfl_xor(ks, 32);
        ksq += __shfl_xor(ksq, 16); ksq += __shfl_xor(ksq, 32);
        vs  += __shfl_xor(vs, 16);  vs  += __shfl_xor(vs, 32);
        vsq += __shfl_xor(vsq, 16); vsq += __shfl_xor(vsq, 32);
        float muk = ks * 0.03125f, muv = vs * 0.03125f;
        float rsk = rsqrtf(fmaxf(ksq * 0.03125f - muk * muk, 0.f) + 1e-5f);
        float rsv = rsqrtf(fmaxf(vsq * 0.03125f - muv * muv, 0.f) + 1e-5f);
        int n = wr * 64 + mi * 16 + lrow;
        #pragma unroll
        for (int ni = 0; ni < 4; ++ni){
            float mu = (ni < 2) ? muk : muv;
            float rs = (ni < 2) ? rsk : rsv;
            #pragma unroll
            for (int r = 0; r < 4; ++r){
                int d = (ni & 1) * 16 + q4 + r;
                float val = (acc[mi][ni][r] - mu) * rs * lwv[ni][r] + lbv[ni][r];
                int byteoff = ((wc * 2 + (ni >> 1)) << 13) + (d << 8) + (n << 1);
                byteoff ^= (d & 7) << 4;
                *(u16*)((char*)sh + byteoff) = f2bf(val);
            }
        }
    }
    __syncthreads();

    if (wid < 2){
        f32x4 a2[2][2];
        #pragma unroll
        for (int i = 0; i < 2; ++i)
            #pragma unroll
            for (int j = 0; j < 2; ++j) a2[i][j] = (f32x4)0.0f;
        #pragma unroll
        for (int ks2 = 0; ks2 < 4; ++ks2){
            int n0 = q * 8 + ks2 * 32;
            short8 kf[2], vf[2];
            #pragma unroll
            for (int mi = 0; mi < 2; ++mi){
                int d = mi * 16 + lrow;
                int bko = ((wid * 2 + 0) << 13) + (d << 8) + (n0 << 1);
                int bvo = ((wid * 2 + 1) << 13) + (d << 8) + (n0 << 1);
                bko ^= (d & 7) << 4;
                bvo ^= (d & 7) << 4;
                kf[mi] = *(const short8*)((char*)sh + bko);
                vf[mi] = *(const short8*)((char*)sh + bvo);
            }
            #pragma unroll
            for (int mi = 0; mi < 2; ++mi)
                #pragma unroll
                for (int ni = 0; ni < 2; ++ni)
                    a2[mi][ni] = __builtin_amdgcn_mfma_f32_16x16x32_bf16(
                        kf[mi], vf[ni], a2[mi][ni], 0, 0, 0);
        }
        float* dst = kvpart + (((size_t)(bz * 128 + by)) * 8 + 2 * bx + wid) * 1024;
        #pragma unroll
        for (int mi = 0; mi < 2; ++mi)
            #pragma unroll
            for (int ni = 0; ni < 2; ++ni)
                #pragma unroll
                for (int r = 0; r < 4; ++r)
                    dst[(mi * 16 + q4 + r) * 32 + ni * 16 + lrow] = a2[mi][ni][r];
    }
}

// ---------------------------------------------------------------------------
// K2: reduce kv partials (128 chunks), form wq_eff[b,h,e,c] and beff[b,h,e]
// ---------------------------------------------------------------------------
__global__ __launch_bounds__(256) void k_wqeff(const float* __restrict__ kvpart,
                                               const float* __restrict__ w_qkv,
                                               const float* __restrict__ b_qkv,
                                               u16* __restrict__ wq_eff_b,
                                               float* __restrict__ beff){
    __shared__ float kv[1024];   // [d*32 + e]
    int h = blockIdx.x, b = blockIdx.y;
    int t = threadIdx.x;
    f32x4 s = (f32x4)0.0f;
    for (int p = 0; p < 128; ++p){
        f32x4 v = *(const f32x4*)(kvpart + (((size_t)b * 128 + p) * 8 + h) * 1024 + t * 4);
        s = s + v;
    }
    const float invN = 1.0f / (float)HW_N;
    #pragma unroll
    for (int i = 0; i < 4; ++i) kv[t * 4 + i] = s[i] * invN;
    __syncthreads();

    float wcol[32];
    #pragma unroll
    for (int d = 0; d < 32; ++d)
        wcol[d] = w_qkv[((size_t)(h * 96 + d)) * 256 + t];
    for (int e = 0; e < 32; ++e){
        float s2 = 0.f;
        #pragma unroll
        for (int d = 0; d < 32; ++d) s2 += wcol[d] * kv[d * 32 + e];
        wq_eff_b[(((size_t)b * 256) + h * 32 + e) * 256 + t] = f2bf(s2);
    }
    if (t < 32){
        float s3 = 0.f;
        #pragma unroll
        for (int d = 0; d < 32; ++d) s3 += b_qkv[h * 96 + d] * kv[d * 32 + t];
        beff[b * 256 + h * 32 + t] = s3;
    }
}

// ---------------------------------------------------------------------------
// K3 fused: three chained GEMMs on a persistent 64-row LDS panel.
//   stage1: ret = xb@wqeff^T + beff + xb(resid from LDS)     -> I (in place)
//   stage2: y1  = gelu(ret@w_o1^T + b_o1)                    -> I (in place)
//   stage3: out[b,o,n] = y1@w_o2^T + b_o2 + x[b,o,n]         -> global fp32
// I: 32 KB [64 n][256 c] bf16, 16B-slot XOR swizzle (slot ^= n&7).
// B: 2 x 16 KB double buffer [256 o][32 k], slot ^= o&3; 2-phase prefetch
// (issue next-kt global_load_lds BEFORE ds_read+MFMA of current kt).
// Block remap: batch-per-XCD (dispatch d: bz = d&7, nb = d>>3).
// ---------------------------------------------------------------------------
#define STAGE_B(BT, KT, BUF) do {                                             \
    _Pragma("unroll")                                                         \
    for (int it_ = 0; it_ < 4; ++it_){                                        \
        int f_ = it_ * 256 + t;                                               \
        int o_ = f_ >> 2, sl_ = f_ & 3;                                       \
        GLD16(&(BT)[(size_t)o_ * 256 + (KT) * 32 + (sl_ ^ (o_ & 3)) * 8],     \
              &(BUF)[f_ * 8]);                                                \
    }                                                                         \
} while(0)

#define ZACC do {                                                             \
    _Pragma("unroll") for (int i_ = 0; i_ < 4; ++i_)                          \
    _Pragma("unroll") for (int j_ = 0; j_ < 4; ++j_)                          \
        acc[i_][j_] = (f32x4)0.0f;                                            \
} while(0)

#define KLOOP(BT, SWAPPED) do {                                               \
    for (int kt = 0; kt < 8; ++kt){                                           \
        int cur = kt & 1;                                                     \
        if (kt < 7) STAGE_B(BT, kt + 1, Bs[cur ^ 1]);                         \
        short8 af[4], bf[4];                                                  \
        _Pragma("unroll")                                                     \
        for (int mi = 0; mi < 4; ++mi){                                       \
            int n_ = mi * 16 + lrow;                                          \
            int sl_ = (kt * 4 + q) ^ (n_ & 7);                                \
            af[mi] = *(const short8*)((const char*)I + n_ * 512 + (sl_ << 4));\
        }                                                                     \
        _Pragma("unroll")                                                     \
        for (int ni = 0; ni < 4; ++ni){                                       \
            int o_ = wid * 64 + ni * 16 + lrow;                               \
            bf[ni] = *(const short8*)((const char*)Bs[cur] + o_ * 64          \
                                      + ((q ^ (o_ & 3)) << 4));               \
        }                                                                     \
        _Pragma("unroll")                                                     \
        for (int mi = 0; mi < 4; ++mi)                                        \
            _Pragma("unroll")                                                 \
            for (int ni = 0; ni < 4; ++ni)                                    \
                acc[mi][ni] = (SWAPPED)                                       \
                    ? __builtin_amdgcn_mfma_f32_16x16x32_bf16(                \
                          bf[ni], af[mi], acc[mi][ni], 0, 0, 0)               \
                    : __builtin_amdgcn_mfma_f32_16x16x32_bf16(                \
                          af[mi], bf[ni], acc[mi][ni], 0, 0, 0);              \
        __syncthreads();                                                      \
    }                                                                         \
} while(0)

__global__ __launch_bounds__(256, 2) void k_fused3(const u16* __restrict__ xb,
                                                   const u16* __restrict__ wq_effb,
                                                   const float* __restrict__ beff,
                                                   const u16* __restrict__ w_o1_b,
                                                   const float* __restrict__ b_o1,
                                                   const u16* __restrict__ w_o2_b,
                                                   const float* __restrict__ b_o2,
                                                   const float* __restrict__ x,
                                                   float* __restrict__ out){
    __shared__ __align__(16) u16 I[16384];        // 32 KB persistent panel
    __shared__ __align__(16) u16 Bs[2][8192];     // 2 x 16 KB B staging

    int d = blockIdx.x;                 // 2048 blocks
    int bz = d & 7, nb = d >> 3;        // batch-per-XCD remap
    size_t row0 = (size_t)bz * HW_N + (size_t)nb * 64;

    int t = threadIdx.x, wid = t >> 6, lane = t & 63;
    int lrow = lane & 15, q = lane >> 4, q4 = q * 4;

    const u16* B1 = wq_effb + (size_t)bz * 65536;

    // ---- preload xb panel into I (pre-swizzled source, linear LDS dest) ----
    #pragma unroll
    for (int it = 0; it < 8; ++it){
        int f = it * 256 + t;
        int n = f >> 5, slot = f & 31;
        GLD16(&xb[(row0 + n) * 256 + (size_t)((slot ^ (n & 7)) * 8)], &I[f * 8]);
    }
    STAGE_B(B1, 0, Bs[0]);
    __syncthreads();

    f32x4 acc[4][4];

    // ================= stage 1: ret = I @ wqeff^T + beff + I ================
    ZACC;
    KLOOP(B1, true);
    STAGE_B(w_o1_b, 0, Bs[0]);                    // prefetch stage-2 kt0
    #pragma unroll
    for (int ni = 0; ni < 4; ++ni){
        int o0 = wid * 64 + ni * 16 + q4;
        f32x4 be = *(const f32x4*)&beff[bz * 256 + o0];
        #pragma unroll
        for (int mi = 0; mi < 4; ++mi){
            int n = mi * 16 + lrow;
            int byte = (n * 512 + o0 * 2) ^ ((n & 7) << 4);
            short4v rv = *(const short4v*)((const char*)I + byte);
            short4v pk;
            #pragma unroll
            for (int r = 0; r < 4; ++r)
                pk[r] = (short)f2bf(acc[mi][ni][r] + be[r] + bf2f((u16)rv[r]));
            *(short4v*)((char*)I + byte) = pk;
        }
    }
    __syncthreads();

    // ================= stage 2: y1 = gelu(I @ w_o1^T + b_o1) ================
    ZACC;
    KLOOP(w_o1_b, true);
    STAGE_B(w_o2_b, 0, Bs[0]);                    // prefetch stage-3 kt0
    #pragma unroll
    for (int ni = 0; ni < 4; ++ni){
        int o0 = wid * 64 + ni * 16 + q4;
        f32x4 bo = *(const f32x4*)&b_o1[o0];
        #pragma unroll
        for (int mi = 0; mi < 4; ++mi){
            int n = mi * 16 + lrow;
            int byte = (n * 512 + o0 * 2) ^ ((n & 7) << 4);
            short4v pk;
            #pragma unroll
            for (int r = 0; r < 4; ++r){
                float v = acc[mi][ni][r] + bo[r];
                v = 0.5f * v * (1.0f + erff(v * 0.70710678118654752f));
                pk[r] = (short)f2bf(v);
            }
            *(short4v*)((char*)I + byte) = pk;
        }
    }
    __syncthreads();

    // ================= stage 3: out = I @ w_o2^T + b_o2 + x =================
    ZACC;
    KLOOP(w_o2_b, false);
    #pragma unroll
    for (int ni = 0; ni < 4; ++ni){
        int o = wid * 64 + ni * 16 + lrow;
        float bo = b_o2[o];
        size_t base = ((size_t)bz * 256 + o) * HW_N + (size_t)nb * 64;
        #pragma unroll
        for (int mi = 0; mi < 4; ++mi){
            int n0 = mi * 16 + q4;
            f32x4 xv = *(const f32x4*)&x[base + n0];
            f32x4 ov;
            #pragma unroll
            for (int r = 0; r < 4; ++r) ov[r] = acc[mi][ni][r] + bo + xv[r];
            *(f32x4*)&out[base + n0] = ov;
        }
    }
}

// ---------------------------------------------------------------------------
extern "C" void kernel_launch(void* const* d_in, const int* in_sizes, int n_in,
                              void* d_out, int out_size, void* d_ws, size_t ws_size,
                              hipStream_t stream){
    const float* x     = (const float*)d_in[0];
    const float* w_qkv = (const float*)d_in[1];
    const float* b_qkv = (const float*)d_in[2];
    const float* kln_w = (const float*)d_in[3];
    const float* kln_b = (const float*)d_in[4];
    const float* vln_w = (const float*)d_in[5];
    const float* vln_b = (const float*)d_in[6];
    const float* w_o1  = (const float*)d_in[7];
    const float* b_o1  = (const float*)d_in[8];
    const float* w_o2  = (const float*)d_in[9];
    const float* b_o2  = (const float*)d_in[10];
    float* out = (float*)d_out;

    const size_t MB = 1u << 20;
    if (ws_size < 266 * MB) return;

    char* ws = (char*)d_ws;
    u16*   xb      = (u16*)(ws);                     // 64 MB
    float* kvpart  = (float*)(ws + 192 * MB);        // 32 MB
    char*  sm      = ws + 264 * MB;
    u16*   wkv_b   = (u16*)sm;                       // 256KB
    float* bkv_re  = (float*)(sm + 256 * 1024);      // 2KB
    u16*   w_o1_b  = (u16*)(sm + 260 * 1024);        // 128KB
    u16*   w_o2_b  = (u16*)(sm + 392 * 1024);        // 128KB
    u16*   wq_effb = (u16*)(sm + 524 * 1024);        // 1MB
    float* beff    = (float*)(sm + 1572 * 1024);     // 8KB

    // K0a: transpose+cast x -> xb
    k_transpose_cast<<<dim3(HW_N / 64, CCH / 64, BATCH), 256, 0, stream>>>(x, xb);
    // K0b: weight prep
    k_weight_prep<<<dim3(1024), 256, 0, stream>>>(w_qkv, b_qkv, w_o1, w_o2,
                                                  wkv_b, bkv_re, w_o1_b, w_o2_b);
    // K1: k/v projection + LN + kv partial sums
    k_gemm_kv<<<dim3(4, 128, BATCH), 256, 0, stream>>>(
        xb, wkv_b, bkv_re, kln_w, kln_b, vln_w, vln_b, kvpart);
    // K2: reduce partials, build per-batch effective q-weights
    k_wqeff<<<dim3(NHEAD, BATCH), 256, 0, stream>>>(kvpart, w_qkv, b_qkv, wq_effb, beff);
    // K3 fused: att+resid -> gelu-MLP -> out (+x), one kernel
    k_fused3<<<dim3(2048), 256, 0, stream>>>(
        xb, wq_effb, beff, w_o1_b, b_o1, w_o2_b, b_o2, x, out);
}